// Round 1
// baseline (2000.654 us; speedup 1.0000x reference)
//
#include <hip/hip_runtime.h>
#include <cstdint>

#define N_NODES 50000
#define N_EDGES 800000
#define DIM     256
#define BSZ     256
#define ND_     5000
#define KNB     16
#define ER_     20000
#define LAM     0.7f

// ---------------------------------------------------------------- GEMM fp32
// C[M,256] = A[M,256] @ B[256,256], 128x128 tile, 8x8 micro-tile, KC=16
#define BM 128
#define BN 128
#define KC 16

__global__ __launch_bounds__(256)
void gemm_f32_kernel(const float* __restrict__ A, const float* __restrict__ B,
                     float* __restrict__ C, int M) {
    __shared__ float As[KC][BM];   // transposed: As[k][m]
    __shared__ float Bs[KC][BN];   // Bs[k][n]
    const int bm = blockIdx.x * BM;
    const int bn = blockIdx.y * BN;
    const int tid = threadIdx.x;
    const int tx = tid & 15;   // n
    const int ty = tid >> 4;   // m

    float acc[8][8];
#pragma unroll
    for (int i = 0; i < 8; ++i)
#pragma unroll
        for (int j = 0; j < 8; ++j) acc[i][j] = 0.f;

    for (int k0 = 0; k0 < 256; k0 += KC) {
        // stage A: 128 rows x 16 k = 512 float4, 2 per thread
#pragma unroll
        for (int u = 0; u < 2; ++u) {
            int idx = tid + u * 256;      // 0..511
            int row = idx >> 2;           // 0..127
            int kq  = idx & 3;
            int grow = bm + row;
            float4 v = make_float4(0.f, 0.f, 0.f, 0.f);
            if (grow < M)
                v = *(const float4*)(A + (size_t)grow * 256 + k0 + kq * 4);
            As[kq * 4 + 0][row] = v.x;
            As[kq * 4 + 1][row] = v.y;
            As[kq * 4 + 2][row] = v.z;
            As[kq * 4 + 3][row] = v.w;
        }
        // stage B: 16 rows x 128 cols = 512 float4, 2 per thread
#pragma unroll
        for (int u = 0; u < 2; ++u) {
            int idx = tid + u * 256;
            int kr = idx >> 5;            // 0..15
            int cq = idx & 31;            // 0..31
            float4 v = *(const float4*)(B + (size_t)(k0 + kr) * 256 + bn + cq * 4);
            *(float4*)&Bs[kr][cq * 4] = v;
        }
        __syncthreads();
#pragma unroll
        for (int k = 0; k < KC; ++k) {
            float a[8], b[8];
            *(float4*)&a[0] = *(const float4*)&As[k][ty * 8];
            *(float4*)&a[4] = *(const float4*)&As[k][ty * 8 + 4];
            *(float4*)&b[0] = *(const float4*)&Bs[k][tx * 8];
            *(float4*)&b[4] = *(const float4*)&Bs[k][tx * 8 + 4];
#pragma unroll
            for (int i = 0; i < 8; ++i)
#pragma unroll
                for (int j = 0; j < 8; ++j)
                    acc[i][j] = fmaf(a[i], b[j], acc[i][j]);
        }
        __syncthreads();
    }
#pragma unroll
    for (int i = 0; i < 8; ++i) {
        int grow = bm + ty * 8 + i;
        if (grow < M) {
            float* cp = C + (size_t)grow * 256 + bn + tx * 8;
            *(float4*)cp       = *(float4*)&acc[i][0];
            *(float4*)(cp + 4) = *(float4*)&acc[i][4];
        }
    }
}

// ---------------------------------------------------- per-node attention dots
// hs[n] = dot(h[n,:], a_src), hd[n] = dot(h[n,:], a_dst); 1 wave per node
__global__ __launch_bounds__(256)
void node_dots_kernel(const float* __restrict__ h,
                      const float* __restrict__ a_src,
                      const float* __restrict__ a_dst,
                      float* __restrict__ hs, float* __restrict__ hd) {
    int node = blockIdx.x * 4 + (threadIdx.x >> 6);
    int lane = threadIdx.x & 63;
    if (node >= N_NODES) return;
    float4 v  = ((const float4*)(h + (size_t)node * DIM))[lane];
    float4 as = ((const float4*)a_src)[lane];
    float4 ad = ((const float4*)a_dst)[lane];
    float ssum = v.x * as.x + v.y * as.y + v.z * as.z + v.w * as.w;
    float dsum = v.x * ad.x + v.y * ad.y + v.z * ad.z + v.w * ad.w;
#pragma unroll
    for (int off = 32; off; off >>= 1) {
        ssum += __shfl_down(ssum, off);
        dsum += __shfl_down(dsum, off);
    }
    if (lane == 0) { hs[node] = ssum; hd[node] = dsum; }
}

// --------------------------------------------- order-preserving f32<->u32 map
__device__ __forceinline__ unsigned f32_enc(float f) {
    unsigned u = __float_as_uint(f);
    return (u & 0x80000000u) ? ~u : (u | 0x80000000u);
}
__device__ __forceinline__ float f32_dec(unsigned u) {
    u = (u & 0x80000000u) ? (u & 0x7FFFFFFFu) : ~u;
    return __uint_as_float(u);
}

// segment max: menc init 0 == "-inf"; finite e always encodes > 0
__global__ __launch_bounds__(256)
void edge_max_kernel(const int* __restrict__ ei,
                     const float* __restrict__ hs, const float* __restrict__ hd,
                     unsigned* __restrict__ menc) {
    int e = blockIdx.x * 256 + threadIdx.x;
    if (e >= N_EDGES) return;
    int s = ei[e], d = ei[N_EDGES + e];
    float v = hs[s] + hd[d];
    v = (v >= 0.f) ? v : 0.2f * v;
    atomicMax(&menc[d], f32_enc(v));
}

__global__ __launch_bounds__(256)
void edge_exp_kernel(const int* __restrict__ ei,
                     const float* __restrict__ hs, const float* __restrict__ hd,
                     const unsigned* __restrict__ menc,
                     float* __restrict__ p, float* __restrict__ z) {
    int e = blockIdx.x * 256 + threadIdx.x;
    if (e >= N_EDGES) return;
    int s = ei[e], d = ei[N_EDGES + e];
    float v = hs[s] + hd[d];
    v = (v >= 0.f) ? v : 0.2f * v;
    float m = f32_dec(menc[d]);
    float pe = expf(v - m);
    p[e] = pe;
    atomicAdd(&z[d], pe);
}

// out[dst,:] += (p/(z+eps)) * h[src,:]  — atomic scatter, 8 edges per block
#define EPB 8
__global__ __launch_bounds__(256)
void edge_aggr_kernel(const int* __restrict__ ei,
                      const float* __restrict__ p, const float* __restrict__ z,
                      const float* __restrict__ h, float* __restrict__ out) {
    int t = threadIdx.x;
    int e0 = blockIdx.x * EPB;
#pragma unroll
    for (int u = 0; u < EPB; ++u) {
        int e = e0 + u;
        if (e >= N_EDGES) break;
        int s = ei[e], d = ei[N_EDGES + e];
        float alpha = p[e] / (z[d] + 1e-16f);
        atomicAdd(&out[(size_t)d * DIM + t], alpha * h[(size_t)s * DIM + t]);
    }
}

// ------------------------------------------------------------- bias (+silu)
__global__ __launch_bounds__(256)
void bias_silu_kernel(float4* __restrict__ buf, const float* __restrict__ bias,
                      int do_silu) {
    size_t i = (size_t)blockIdx.x * 256 + threadIdx.x;   // float4 index
    float4 v = buf[i];
    float4 bb = ((const float4*)bias)[i & 63];
    v.x += bb.x; v.y += bb.y; v.z += bb.z; v.w += bb.w;
    if (do_silu) {
        v.x = v.x / (1.f + expf(-v.x));
        v.y = v.y / (1.f + expf(-v.y));
        v.z = v.z / (1.f + expf(-v.z));
        v.w = v.w / (1.f + expf(-v.w));
    }
    buf[i] = v;
}

// --------------------------------------------- precompute c[b] (deg counting)
__global__ __launch_bounds__(256)
void deg_c_kernel(const int* __restrict__ rel, const int* __restrict__ head,
                  const int* __restrict__ g2l, const int* __restrict__ res,
                  float* __restrict__ cvals) {
    int b = blockIdx.x;
    int r = rel[b];
    if (r < 4 || r > 6) { if (threadIdx.x == 0) cvals[b] = 0.f; return; }
    int local = g2l[head[b]];
    const int* rr = res + (size_t)(r - 4) * ER_;
    int cnt = 0;
    for (int i = threadIdx.x; i < ER_; i += 256) cnt += (rr[i] == local);
    __shared__ int sdeg;
    if (threadIdx.x == 0) sdeg = 0;
    __syncthreads();
#pragma unroll
    for (int off = 32; off; off >>= 1) cnt += __shfl_down(cnt, off);
    if ((threadIdx.x & 63) == 0) atomicAdd(&sdeg, cnt);
    __syncthreads();
    if (threadIdx.x == 0)
        cvals[b] = LAM * expf(-LAM * (float)sdeg) + 0.2f;
}

// ------------------------------------------ sequential scan (single block)
__global__ __launch_bounds__(256)
void scan_kernel(float* __restrict__ emb, const int* __restrict__ head,
                 const int* __restrict__ rel, const int* __restrict__ g2l,
                 const int* __restrict__ nbs, const float* __restrict__ wts,
                 const float* __restrict__ cvals) {
    int t = threadIdx.x;
    for (int b = 0; b < BSZ; ++b) {
        int r = rel[b];                 // uniform across block
        if (r >= 4 && r <= 6) {
            int hi = head[b];
            int local = g2l[hi];
            float c = cvals[b];
            const int* nb   = nbs + (size_t)local * KNB;
            const float* w  = wts + (size_t)local * KNB;
            float vec = 0.f;
#pragma unroll
            for (int k = 0; k < KNB; ++k)
                vec = fmaf(w[k], emb[(size_t)nb[k] * DIM + t], vec);
            float old = emb[(size_t)hi * DIM + t];
            emb[(size_t)hi * DIM + t] = c * vec + (1.f - c) * old;
            __syncthreads();            // make write visible before next step
        }
    }
}

// ------------------------------------------------------------------ decode
__global__ __launch_bounds__(256)
void decode_kernel(const float* __restrict__ emb, const int* __restrict__ head,
                   const int* __restrict__ rel, const int* __restrict__ tail,
                   const float* __restrict__ rel_emb, float* __restrict__ out) {
    int b = blockIdx.x, t = threadIdx.x;
    float v = emb[(size_t)head[b] * DIM + t] *
              rel_emb[(size_t)rel[b] * DIM + t] *
              emb[(size_t)tail[b] * DIM + t];
    __shared__ float red[4];
#pragma unroll
    for (int off = 32; off; off >>= 1) v += __shfl_down(v, off);
    int lane = t & 63, w = t >> 6;
    if (lane == 0) red[w] = v;
    __syncthreads();
    if (t == 0) {
        float s = red[0] + red[1] + red[2] + red[3];
        out[b] = 1.f / (1.f + expf(-s));
    }
}

// ------------------------------------------------------------------ launch
extern "C" void kernel_launch(void* const* d_in, const int* in_sizes, int n_in,
                              void* d_out, int out_size, void* d_ws, size_t ws_size,
                              hipStream_t stream) {
    const float* x        = (const float*)d_in[0];
    const int*   ei       = (const int*)d_in[1];
    const int*   head     = (const int*)d_in[2];
    const int*   rel      = (const int*)d_in[3];
    const int*   tail     = (const int*)d_in[4];
    const int*   g2l      = (const int*)d_in[5];
    const int*   res      = (const int*)d_in[6];
    const int*   nbs      = (const int*)d_in[7];
    const float* wts      = (const float*)d_in[8];
    const float* W1       = (const float*)d_in[9];
    const float* a1s      = (const float*)d_in[10];
    const float* a1d      = (const float*)d_in[11];
    const float* b1       = (const float*)d_in[12];
    const float* W2       = (const float*)d_in[13];
    const float* a2s      = (const float*)d_in[14];
    const float* a2d      = (const float*)d_in[15];
    const float* b2       = (const float*)d_in[16];
    const float* rel_emb  = (const float*)d_in[17];
    float* out = (float*)d_out;

    char* ws = (char*)d_ws;
    size_t off = 0;
    auto alloc = [&](size_t bytes) {
        void* pp = ws + off;
        off += (bytes + 255) & ~(size_t)255;
        return pp;
    };
    float*    bufA  = (float*)alloc((size_t)N_NODES * DIM * 4);  // h (gemm out)
    float*    bufB  = (float*)alloc((size_t)N_NODES * DIM * 4);  // aggregated
    float*    hs    = (float*)alloc((size_t)N_NODES * 4);
    float*    hd    = (float*)alloc((size_t)N_NODES * 4);
    unsigned* menc  = (unsigned*)alloc((size_t)N_NODES * 4);
    float*    z     = (float*)alloc((size_t)N_NODES * 4);
    float*    p     = (float*)alloc((size_t)N_EDGES * 4);
    float*    cvals = (float*)alloc((size_t)BSZ * 4);

    dim3 gemmGrid((N_NODES + BM - 1) / BM, 256 / BN);
    const int edgeBlocks = (N_EDGES + 255) / 256;
    const int aggrBlocks = (N_EDGES + EPB - 1) / EPB;
    const int biasBlocks = N_NODES * (DIM / 4) / 256;   // 12500

    // ---------------- layer 1 ----------------
    hipMemsetAsync(menc, 0, (size_t)N_NODES * 4, stream);
    hipMemsetAsync(z,    0, (size_t)N_NODES * 4, stream);
    hipMemsetAsync(bufB, 0, (size_t)N_NODES * DIM * 4, stream);
    gemm_f32_kernel<<<gemmGrid, 256, 0, stream>>>(x, W1, bufA, N_NODES);
    node_dots_kernel<<<(N_NODES + 3) / 4, 256, 0, stream>>>(bufA, a1s, a1d, hs, hd);
    edge_max_kernel<<<edgeBlocks, 256, 0, stream>>>(ei, hs, hd, menc);
    edge_exp_kernel<<<edgeBlocks, 256, 0, stream>>>(ei, hs, hd, menc, p, z);
    edge_aggr_kernel<<<aggrBlocks, 256, 0, stream>>>(ei, p, z, bufA, bufB);
    bias_silu_kernel<<<biasBlocks, 256, 0, stream>>>((float4*)bufB, b1, 1);

    // ---------------- layer 2 ----------------
    hipMemsetAsync(menc, 0, (size_t)N_NODES * 4, stream);
    hipMemsetAsync(z,    0, (size_t)N_NODES * 4, stream);
    gemm_f32_kernel<<<gemmGrid, 256, 0, stream>>>(bufB, W2, bufA, N_NODES);
    // bufB free once the GEMM has consumed it (stream order)
    hipMemsetAsync(bufB, 0, (size_t)N_NODES * DIM * 4, stream);
    node_dots_kernel<<<(N_NODES + 3) / 4, 256, 0, stream>>>(bufA, a2s, a2d, hs, hd);
    edge_max_kernel<<<edgeBlocks, 256, 0, stream>>>(ei, hs, hd, menc);
    edge_exp_kernel<<<edgeBlocks, 256, 0, stream>>>(ei, hs, hd, menc, p, z);
    edge_aggr_kernel<<<aggrBlocks, 256, 0, stream>>>(ei, p, z, bufA, bufB);
    bias_silu_kernel<<<biasBlocks, 256, 0, stream>>>((float4*)bufB, b2, 0);

    // ---------------- scan + decode ----------------
    deg_c_kernel<<<BSZ, 256, 0, stream>>>(rel, head, g2l, res, cvals);
    scan_kernel<<<1, 256, 0, stream>>>(bufB, head, rel, g2l, nbs, wts, cvals);
    decode_kernel<<<BSZ, 256, 0, stream>>>(bufB, head, rel, tail, rel_emb, out);
}

// Round 2
// 935.833 us; speedup vs baseline: 2.1378x; 2.1378x over previous
//
#include <hip/hip_runtime.h>
#include <cstdint>

#define N_NODES 50000
#define N_EDGES 800000
#define DIM     256
#define BSZ     256
#define ND_     5000
#define KNB     16
#define ER_     20000
#define LAM     0.7f

// ---------------------------------------------------------------- GEMM fp32
// C[M,256] = A[M,256] @ B[256,256], 128x128 tile, 8x8 micro-tile, KC=16
#define BM 128
#define BN 128
#define KC 16

__global__ __launch_bounds__(256)
void gemm_f32_kernel(const float* __restrict__ A, const float* __restrict__ B,
                     float* __restrict__ C, int M) {
    __shared__ float As[KC][BM];   // transposed: As[k][m]
    __shared__ float Bs[KC][BN];   // Bs[k][n]
    const int bm = blockIdx.x * BM;
    const int bn = blockIdx.y * BN;
    const int tid = threadIdx.x;
    const int tx = tid & 15;   // n
    const int ty = tid >> 4;   // m

    float acc[8][8];
#pragma unroll
    for (int i = 0; i < 8; ++i)
#pragma unroll
        for (int j = 0; j < 8; ++j) acc[i][j] = 0.f;

    for (int k0 = 0; k0 < 256; k0 += KC) {
#pragma unroll
        for (int u = 0; u < 2; ++u) {
            int idx = tid + u * 256;      // 0..511
            int row = idx >> 2;           // 0..127
            int kq  = idx & 3;
            int grow = bm + row;
            float4 v = make_float4(0.f, 0.f, 0.f, 0.f);
            if (grow < M)
                v = *(const float4*)(A + (size_t)grow * 256 + k0 + kq * 4);
            As[kq * 4 + 0][row] = v.x;
            As[kq * 4 + 1][row] = v.y;
            As[kq * 4 + 2][row] = v.z;
            As[kq * 4 + 3][row] = v.w;
        }
#pragma unroll
        for (int u = 0; u < 2; ++u) {
            int idx = tid + u * 256;
            int kr = idx >> 5;            // 0..15
            int cq = idx & 31;            // 0..31
            float4 v = *(const float4*)(B + (size_t)(k0 + kr) * 256 + bn + cq * 4);
            *(float4*)&Bs[kr][cq * 4] = v;
        }
        __syncthreads();
#pragma unroll
        for (int k = 0; k < KC; ++k) {
            float a[8], b[8];
            *(float4*)&a[0] = *(const float4*)&As[k][ty * 8];
            *(float4*)&a[4] = *(const float4*)&As[k][ty * 8 + 4];
            *(float4*)&b[0] = *(const float4*)&Bs[k][tx * 8];
            *(float4*)&b[4] = *(const float4*)&Bs[k][tx * 8 + 4];
#pragma unroll
            for (int i = 0; i < 8; ++i)
#pragma unroll
                for (int j = 0; j < 8; ++j)
                    acc[i][j] = fmaf(a[i], b[j], acc[i][j]);
        }
        __syncthreads();
    }
#pragma unroll
    for (int i = 0; i < 8; ++i) {
        int grow = bm + ty * 8 + i;
        if (grow < M) {
            float* cp = C + (size_t)grow * 256 + bn + tx * 8;
            *(float4*)cp       = *(float4*)&acc[i][0];
            *(float4*)(cp + 4) = *(float4*)&acc[i][4];
        }
    }
}

// ---------------------------------------------------- per-node attention dots
__global__ __launch_bounds__(256)
void node_dots_kernel(const float* __restrict__ h,
                      const float* __restrict__ a_src,
                      const float* __restrict__ a_dst,
                      float* __restrict__ hs, float* __restrict__ hd) {
    int node = blockIdx.x * 4 + (threadIdx.x >> 6);
    int lane = threadIdx.x & 63;
    if (node >= N_NODES) return;
    float4 v  = ((const float4*)(h + (size_t)node * DIM))[lane];
    float4 as = ((const float4*)a_src)[lane];
    float4 ad = ((const float4*)a_dst)[lane];
    float ssum = v.x * as.x + v.y * as.y + v.z * as.z + v.w * as.w;
    float dsum = v.x * ad.x + v.y * ad.y + v.z * ad.z + v.w * ad.w;
#pragma unroll
    for (int off = 32; off; off >>= 1) {
        ssum += __shfl_down(ssum, off);
        dsum += __shfl_down(dsum, off);
    }
    if (lane == 0) { hs[node] = ssum; hd[node] = dsum; }
}

// -------------------------------------------------------------- CSR build
__global__ __launch_bounds__(256)
void hist_kernel(const int* __restrict__ ei, int* __restrict__ deg) {
    int e = blockIdx.x * 256 + threadIdx.x;
    if (e < N_EDGES) atomicAdd(&deg[ei[N_EDGES + e]], 1);
}

// single-block exclusive scan of deg[0..N_NODES) -> off[0..N_NODES]
__global__ __launch_bounds__(256)
void scan_offsets_kernel(const int* __restrict__ deg, int* __restrict__ off) {
    __shared__ int sums[256];
    const int t = threadIdx.x;
    const int CH = (N_NODES + 255) / 256;   // 196
    int b0 = t * CH;
    int s = 0;
    for (int i = 0; i < CH; ++i) {
        int idx = b0 + i;
        if (idx < N_NODES) s += deg[idx];
    }
    sums[t] = s;
    __syncthreads();
    for (int o = 1; o < 256; o <<= 1) {
        int v = (t >= o) ? sums[t - o] : 0;
        __syncthreads();
        sums[t] += v;
        __syncthreads();
    }
    int prefix = (t == 0) ? 0 : sums[t - 1];
    for (int i = 0; i < CH; ++i) {
        int idx = b0 + i;
        if (idx < N_NODES) { off[idx] = prefix; prefix += deg[idx]; }
    }
    if (t == 255) off[N_NODES] = sums[255];
}

__global__ __launch_bounds__(256)
void scatter_kernel(const int* __restrict__ ei, const int* __restrict__ off,
                    int* __restrict__ cnt, int* __restrict__ csr_src) {
    int e = blockIdx.x * 256 + threadIdx.x;
    if (e >= N_EDGES) return;
    int d = ei[N_EDGES + e];
    int pos = atomicAdd(&cnt[d], 1);
    csr_src[off[d] + pos] = ei[e];
}

// --------------------------------------- fused GAT edge stage (gather form)
// block = 256 threads = one dst node; online softmax over incoming edges,
// weighted accumulate of h[src] rows, +bias (+silu), single coalesced write.
#define CAP 256
__global__ __launch_bounds__(256)
void gat_aggr_kernel(const int* __restrict__ off, const int* __restrict__ csr_src,
                     const float* __restrict__ hs, const float* __restrict__ hd,
                     const float* __restrict__ h, const float* __restrict__ bias,
                     float* __restrict__ outbuf, int do_silu) {
    const int d = blockIdx.x;
    const int t = threadIdx.x;
    const int beg = off[d], end = off[d + 1];
    __shared__ float pv[CAP];
    __shared__ int   ss[CAP];
    __shared__ float red[4];

    float acc = 0.f;
    float m = -1e30f, z = 0.f;
    const float hdd = hd[d];

    for (int c0 = beg; c0 < end; c0 += CAP) {
        const int cn = min(end - c0, CAP);
        if (t < cn) {
            int s = csr_src[c0 + t];
            ss[t] = s;
            float v = hs[s] + hdd;
            pv[t] = (v >= 0.f) ? v : 0.2f * v;
        }
        __syncthreads();
        // block max
        float lm = (t < cn) ? pv[t] : -1e30f;
#pragma unroll
        for (int o = 32; o; o >>= 1) lm = fmaxf(lm, __shfl_down(lm, o));
        if ((t & 63) == 0) red[t >> 6] = lm;
        __syncthreads();
        float cmax = fmaxf(fmaxf(red[0], red[1]), fmaxf(red[2], red[3]));
        float mn = fmaxf(m, cmax);
        float scale = __expf(m - mn);      // first chunk: exp(-huge) = 0
        z *= scale; acc *= scale;
        __syncthreads();                   // red reads done before reuse
        if (t < cn) pv[t] = __expf(pv[t] - mn);
        __syncthreads();
        float lz = (t < cn) ? pv[t] : 0.f;
#pragma unroll
        for (int o = 32; o; o >>= 1) lz += __shfl_down(lz, o);
        if ((t & 63) == 0) red[t >> 6] = lz;
        __syncthreads();
        z += red[0] + red[1] + red[2] + red[3];
        // weighted accumulate: each thread owns one dim component
        for (int j = 0; j < cn; ++j)
            acc = fmaf(pv[j], h[(size_t)ss[j] * DIM + t], acc);
        __syncthreads();
        m = mn;
    }
    float o = (end > beg) ? acc / (z + 1e-16f) : 0.f;
    o += bias[t];
    if (do_silu) o = o / (1.f + __expf(-o));
    outbuf[(size_t)d * DIM + t] = o;
}

// --------------------------------------------- precompute c[b] (deg counting)
__global__ __launch_bounds__(256)
void deg_c_kernel(const int* __restrict__ rel, const int* __restrict__ head,
                  const int* __restrict__ g2l, const int* __restrict__ res,
                  float* __restrict__ cvals) {
    int b = blockIdx.x;
    int r = rel[b];
    if (r < 4 || r > 6) { if (threadIdx.x == 0) cvals[b] = 0.f; return; }
    int local = g2l[head[b]];
    const int* rr = res + (size_t)(r - 4) * ER_;
    int cnt = 0;
    for (int i = threadIdx.x; i < ER_; i += 256) cnt += (rr[i] == local);
    __shared__ int sdeg;
    if (threadIdx.x == 0) sdeg = 0;
    __syncthreads();
#pragma unroll
    for (int off = 32; off; off >>= 1) cnt += __shfl_down(cnt, off);
    if ((threadIdx.x & 63) == 0) atomicAdd(&sdeg, cnt);
    __syncthreads();
    if (threadIdx.x == 0)
        cvals[b] = LAM * expf(-LAM * (float)sdeg) + 0.2f;
}

// ------------------------------------------ sequential scan (single block)
__global__ __launch_bounds__(256)
void scan_kernel(float* __restrict__ emb, const int* __restrict__ head,
                 const int* __restrict__ rel, const int* __restrict__ g2l,
                 const int* __restrict__ nbs, const float* __restrict__ wts,
                 const float* __restrict__ cvals) {
    int t = threadIdx.x;
    for (int b = 0; b < BSZ; ++b) {
        int r = rel[b];                 // uniform across block
        if (r >= 4 && r <= 6) {
            int hi = head[b];
            int local = g2l[hi];
            float c = cvals[b];
            const int* nb   = nbs + (size_t)local * KNB;
            const float* w  = wts + (size_t)local * KNB;
            float vec = 0.f;
#pragma unroll
            for (int k = 0; k < KNB; ++k)
                vec = fmaf(w[k], emb[(size_t)nb[k] * DIM + t], vec);
            float old = emb[(size_t)hi * DIM + t];
            emb[(size_t)hi * DIM + t] = c * vec + (1.f - c) * old;
            __syncthreads();            // make write visible before next step
        }
    }
}

// ------------------------------------------------------------------ decode
__global__ __launch_bounds__(256)
void decode_kernel(const float* __restrict__ emb, const int* __restrict__ head,
                   const int* __restrict__ rel, const int* __restrict__ tail,
                   const float* __restrict__ rel_emb, float* __restrict__ out) {
    int b = blockIdx.x, t = threadIdx.x;
    float v = emb[(size_t)head[b] * DIM + t] *
              rel_emb[(size_t)rel[b] * DIM + t] *
              emb[(size_t)tail[b] * DIM + t];
    __shared__ float red[4];
#pragma unroll
    for (int off = 32; off; off >>= 1) v += __shfl_down(v, off);
    int lane = t & 63, w = t >> 6;
    if (lane == 0) red[w] = v;
    __syncthreads();
    if (t == 0) {
        float s = red[0] + red[1] + red[2] + red[3];
        out[b] = 1.f / (1.f + expf(-s));
    }
}

// ------------------------------------------------------------------ launch
extern "C" void kernel_launch(void* const* d_in, const int* in_sizes, int n_in,
                              void* d_out, int out_size, void* d_ws, size_t ws_size,
                              hipStream_t stream) {
    const float* x        = (const float*)d_in[0];
    const int*   ei       = (const int*)d_in[1];
    const int*   head     = (const int*)d_in[2];
    const int*   rel      = (const int*)d_in[3];
    const int*   tail     = (const int*)d_in[4];
    const int*   g2l      = (const int*)d_in[5];
    const int*   res      = (const int*)d_in[6];
    const int*   nbs      = (const int*)d_in[7];
    const float* wts      = (const float*)d_in[8];
    const float* W1       = (const float*)d_in[9];
    const float* a1s      = (const float*)d_in[10];
    const float* a1d      = (const float*)d_in[11];
    const float* b1       = (const float*)d_in[12];
    const float* W2       = (const float*)d_in[13];
    const float* a2s      = (const float*)d_in[14];
    const float* a2d      = (const float*)d_in[15];
    const float* b2       = (const float*)d_in[16];
    const float* rel_emb  = (const float*)d_in[17];
    float* out = (float*)d_out;

    char* ws = (char*)d_ws;
    size_t off_b = 0;
    auto alloc = [&](size_t bytes) {
        void* pp = ws + off_b;
        off_b += (bytes + 255) & ~(size_t)255;
        return pp;
    };
    float* bufA    = (float*)alloc((size_t)N_NODES * DIM * 4);  // h (gemm out)
    float* bufB    = (float*)alloc((size_t)N_NODES * DIM * 4);  // layer out
    float* hs      = (float*)alloc((size_t)N_NODES * 4);
    float* hd      = (float*)alloc((size_t)N_NODES * 4);
    int*   deg     = (int*)alloc((size_t)N_NODES * 4);
    int*   offs    = (int*)alloc((size_t)(N_NODES + 1) * 4);
    int*   cnt     = (int*)alloc((size_t)N_NODES * 4);
    int*   csr_src = (int*)alloc((size_t)N_EDGES * 4);
    float* cvals   = (float*)alloc((size_t)BSZ * 4);

    dim3 gemmGrid((N_NODES + BM - 1) / BM, 256 / BN);
    const int edgeBlocks = (N_EDGES + 255) / 256;

    // ---------------- CSR build (graph is layer-invariant) ----------------
    hipMemsetAsync(deg, 0, (size_t)N_NODES * 4, stream);
    hipMemsetAsync(cnt, 0, (size_t)N_NODES * 4, stream);
    hist_kernel<<<edgeBlocks, 256, 0, stream>>>(ei, deg);
    scan_offsets_kernel<<<1, 256, 0, stream>>>(deg, offs);
    scatter_kernel<<<edgeBlocks, 256, 0, stream>>>(ei, offs, cnt, csr_src);

    // ---------------- layer 1 ----------------
    gemm_f32_kernel<<<gemmGrid, 256, 0, stream>>>(x, W1, bufA, N_NODES);
    node_dots_kernel<<<(N_NODES + 3) / 4, 256, 0, stream>>>(bufA, a1s, a1d, hs, hd);
    gat_aggr_kernel<<<N_NODES, 256, 0, stream>>>(offs, csr_src, hs, hd, bufA, b1, bufB, 1);

    // ---------------- layer 2 ----------------
    gemm_f32_kernel<<<gemmGrid, 256, 0, stream>>>(bufB, W2, bufA, N_NODES);
    node_dots_kernel<<<(N_NODES + 3) / 4, 256, 0, stream>>>(bufA, a2s, a2d, hs, hd);
    gat_aggr_kernel<<<N_NODES, 256, 0, stream>>>(offs, csr_src, hs, hd, bufA, b2, bufB, 0);

    // ---------------- scan + decode ----------------
    deg_c_kernel<<<BSZ, 256, 0, stream>>>(rel, head, g2l, res, cvals);
    scan_kernel<<<1, 256, 0, stream>>>(bufB, head, rel, g2l, nbs, wts, cvals);
    decode_kernel<<<BSZ, 256, 0, stream>>>(bufB, head, rel, tail, rel_emb, out);
}

// Round 3
// 831.747 us; speedup vs baseline: 2.4054x; 1.1251x over previous
//
#include <hip/hip_runtime.h>
#include <cstdint>

#define N_NODES 50000
#define N_EDGES 800000
#define DIM     256
#define BSZ     256
#define ND_     5000
#define KNB     16
#define ER_     20000
#define LAM     0.7f

// ---------------------------------------------------------------- GEMM fp32
// C[M,256] = A[M,256] @ B[256,256], 128x128 tile, 8x8 micro-tile, KC=16
#define BM 128
#define BN 128
#define KC 16

__global__ __launch_bounds__(256)
void gemm_f32_kernel(const float* __restrict__ A, const float* __restrict__ B,
                     float* __restrict__ C, int M) {
    __shared__ float As[KC][BM];   // transposed: As[k][m]
    __shared__ float Bs[KC][BN];   // Bs[k][n]
    const int bm = blockIdx.x * BM;
    const int bn = blockIdx.y * BN;
    const int tid = threadIdx.x;
    const int tx = tid & 15;   // n
    const int ty = tid >> 4;   // m

    float acc[8][8];
#pragma unroll
    for (int i = 0; i < 8; ++i)
#pragma unroll
        for (int j = 0; j < 8; ++j) acc[i][j] = 0.f;

    for (int k0 = 0; k0 < 256; k0 += KC) {
#pragma unroll
        for (int u = 0; u < 2; ++u) {
            int idx = tid + u * 256;      // 0..511
            int row = idx >> 2;           // 0..127
            int kq  = idx & 3;
            int grow = bm + row;
            float4 v = make_float4(0.f, 0.f, 0.f, 0.f);
            if (grow < M)
                v = *(const float4*)(A + (size_t)grow * 256 + k0 + kq * 4);
            As[kq * 4 + 0][row] = v.x;
            As[kq * 4 + 1][row] = v.y;
            As[kq * 4 + 2][row] = v.z;
            As[kq * 4 + 3][row] = v.w;
        }
#pragma unroll
        for (int u = 0; u < 2; ++u) {
            int idx = tid + u * 256;
            int kr = idx >> 5;            // 0..15
            int cq = idx & 31;            // 0..31
            float4 v = *(const float4*)(B + (size_t)(k0 + kr) * 256 + bn + cq * 4);
            *(float4*)&Bs[kr][cq * 4] = v;
        }
        __syncthreads();
#pragma unroll
        for (int k = 0; k < KC; ++k) {
            float a[8], b[8];
            *(float4*)&a[0] = *(const float4*)&As[k][ty * 8];
            *(float4*)&a[4] = *(const float4*)&As[k][ty * 8 + 4];
            *(float4*)&b[0] = *(const float4*)&Bs[k][tx * 8];
            *(float4*)&b[4] = *(const float4*)&Bs[k][tx * 8 + 4];
#pragma unroll
            for (int i = 0; i < 8; ++i)
#pragma unroll
                for (int j = 0; j < 8; ++j)
                    acc[i][j] = fmaf(a[i], b[j], acc[i][j]);
        }
        __syncthreads();
    }
#pragma unroll
    for (int i = 0; i < 8; ++i) {
        int grow = bm + ty * 8 + i;
        if (grow < M) {
            float* cp = C + (size_t)grow * 256 + bn + tx * 8;
            *(float4*)cp       = *(float4*)&acc[i][0];
            *(float4*)(cp + 4) = *(float4*)&acc[i][4];
        }
    }
}

// ---------------------------------------------------- per-node attention dots
__global__ __launch_bounds__(256)
void node_dots_kernel(const float* __restrict__ h,
                      const float* __restrict__ a_src,
                      const float* __restrict__ a_dst,
                      float* __restrict__ hs, float* __restrict__ hd) {
    int node = blockIdx.x * 4 + (threadIdx.x >> 6);
    int lane = threadIdx.x & 63;
    if (node >= N_NODES) return;
    float4 v  = ((const float4*)(h + (size_t)node * DIM))[lane];
    float4 as = ((const float4*)a_src)[lane];
    float4 ad = ((const float4*)a_dst)[lane];
    float ssum = v.x * as.x + v.y * as.y + v.z * as.z + v.w * as.w;
    float dsum = v.x * ad.x + v.y * ad.y + v.z * ad.z + v.w * ad.w;
#pragma unroll
    for (int off = 32; off; off >>= 1) {
        ssum += __shfl_down(ssum, off);
        dsum += __shfl_down(dsum, off);
    }
    if (lane == 0) { hs[node] = ssum; hd[node] = dsum; }
}

// -------------------------------------------------------------- CSR build
__global__ __launch_bounds__(256)
void hist_kernel(const int* __restrict__ ei, int* __restrict__ deg) {
    int e = blockIdx.x * 256 + threadIdx.x;
    if (e < N_EDGES) atomicAdd(&deg[ei[N_EDGES + e]], 1);
}

__global__ __launch_bounds__(256)
void scan_offsets_kernel(const int* __restrict__ deg, int* __restrict__ off) {
    __shared__ int sums[256];
    const int t = threadIdx.x;
    const int CH = (N_NODES + 255) / 256;   // 196
    int b0 = t * CH;
    int s = 0;
    for (int i = 0; i < CH; ++i) {
        int idx = b0 + i;
        if (idx < N_NODES) s += deg[idx];
    }
    sums[t] = s;
    __syncthreads();
    for (int o = 1; o < 256; o <<= 1) {
        int v = (t >= o) ? sums[t - o] : 0;
        __syncthreads();
        sums[t] += v;
        __syncthreads();
    }
    int prefix = (t == 0) ? 0 : sums[t - 1];
    for (int i = 0; i < CH; ++i) {
        int idx = b0 + i;
        if (idx < N_NODES) { off[idx] = prefix; prefix += deg[idx]; }
    }
    if (t == 255) off[N_NODES] = sums[255];
}

__global__ __launch_bounds__(256)
void scatter_kernel(const int* __restrict__ ei, const int* __restrict__ off,
                    int* __restrict__ cnt, int* __restrict__ csr_src) {
    int e = blockIdx.x * 256 + threadIdx.x;
    if (e >= N_EDGES) return;
    int d = ei[N_EDGES + e];
    int pos = atomicAdd(&cnt[d], 1);
    csr_src[off[d] + pos] = ei[e];
}

// --------------------------------------- fused GAT edge stage (gather form)
#define CAP 256
__global__ __launch_bounds__(256)
void gat_aggr_kernel(const int* __restrict__ off, const int* __restrict__ csr_src,
                     const float* __restrict__ hs, const float* __restrict__ hd,
                     const float* __restrict__ h, const float* __restrict__ bias,
                     float* __restrict__ outbuf, int do_silu) {
    const int d = blockIdx.x;
    const int t = threadIdx.x;
    const int beg = off[d], end = off[d + 1];
    __shared__ float pv[CAP];
    __shared__ int   ss[CAP];
    __shared__ float red[4];

    float acc = 0.f;
    float m = -1e30f, z = 0.f;
    const float hdd = hd[d];
    const float* __restrict__ hcol = h + t;

    for (int c0 = beg; c0 < end; c0 += CAP) {
        const int cn = min(end - c0, CAP);
        if (t < cn) {
            int s = csr_src[c0 + t];
            ss[t] = s;
            float v = hs[s] + hdd;
            pv[t] = (v >= 0.f) ? v : 0.2f * v;
        }
        __syncthreads();
        // block max
        float lm = (t < cn) ? pv[t] : -1e30f;
#pragma unroll
        for (int o = 32; o; o >>= 1) lm = fmaxf(lm, __shfl_down(lm, o));
        if ((t & 63) == 0) red[t >> 6] = lm;
        __syncthreads();
        float cmax = fmaxf(fmaxf(red[0], red[1]), fmaxf(red[2], red[3]));
        float mn = fmaxf(m, cmax);
        float scale = __expf(m - mn);      // first chunk: exp(-huge) = 0
        z *= scale; acc *= scale;
        __syncthreads();                   // red reads done before reuse
        if (t < cn) pv[t] = __expf(pv[t] - mn);
        __syncthreads();
        float lz = (t < cn) ? pv[t] : 0.f;
#pragma unroll
        for (int o = 32; o; o >>= 1) lz += __shfl_down(lz, o);
        if ((t & 63) == 0) red[t >> 6] = lz;
        __syncthreads();
        z += red[0] + red[1] + red[2] + red[3];
        // weighted accumulate: 4 independent accumulators -> 4 loads in flight
        float a0 = 0.f, a1 = 0.f, a2 = 0.f, a3 = 0.f;
        int j = 0;
        for (; j + 4 <= cn; j += 4) {
            a0 = fmaf(pv[j + 0], hcol[(size_t)ss[j + 0] * DIM], a0);
            a1 = fmaf(pv[j + 1], hcol[(size_t)ss[j + 1] * DIM], a1);
            a2 = fmaf(pv[j + 2], hcol[(size_t)ss[j + 2] * DIM], a2);
            a3 = fmaf(pv[j + 3], hcol[(size_t)ss[j + 3] * DIM], a3);
        }
        for (; j < cn; ++j)
            a0 = fmaf(pv[j], hcol[(size_t)ss[j] * DIM], a0);
        acc += (a0 + a1) + (a2 + a3);
        __syncthreads();
        m = mn;
    }
    float o = (end > beg) ? acc / (z + 1e-16f) : 0.f;
    o += bias[t];
    if (do_silu) o = o / (1.f + __expf(-o));
    outbuf[(size_t)d * DIM + t] = o;
}

// --------------------------------------------- precompute c[b] (deg counting)
__global__ __launch_bounds__(256)
void deg_c_kernel(const int* __restrict__ rel, const int* __restrict__ head,
                  const int* __restrict__ g2l, const int* __restrict__ res,
                  float* __restrict__ cvals) {
    int b = blockIdx.x;
    int r = rel[b];
    if (r < 4 || r > 6) { if (threadIdx.x == 0) cvals[b] = 0.f; return; }
    int local = g2l[head[b]];
    const int* rr = res + (size_t)(r - 4) * ER_;
    int cnt = 0;
    for (int i = threadIdx.x; i < ER_; i += 256) cnt += (rr[i] == local);
    __shared__ int sdeg;
    if (threadIdx.x == 0) sdeg = 0;
    __syncthreads();
#pragma unroll
    for (int off = 32; off; off >>= 1) cnt += __shfl_down(cnt, off);
    if ((threadIdx.x & 63) == 0) atomicAdd(&sdeg, cnt);
    __syncthreads();
    if (threadIdx.x == 0)
        cvals[b] = LAM * expf(-LAM * (float)sdeg) + 0.2f;
}

// -------------------------- parallelized sequential scan -------------------
// Step b writes row hi_b, reads rows nb_b ∪ {hi_b}. Steps whose rows are
// disjoint from every other step's WRITE row (both directions) are order-
// independent -> applied in parallel. The rest (~6%) run sequentially.

// per-step speculative vec from pre-scan emb; init W (write-row) and flags
__global__ __launch_bounds__(256)
void prep_steps_kernel(const float* __restrict__ emb, const int* __restrict__ head,
                       const int* __restrict__ rel, const int* __restrict__ g2l,
                       const int* __restrict__ nbs, const float* __restrict__ wts,
                       float* __restrict__ vecpre, int* __restrict__ W,
                       int* __restrict__ flags) {
    int b = blockIdx.x;
    int t = threadIdx.x;
    int r = rel[b];
    int dis = (r >= 4 && r <= 6);
    if (t == 0) { flags[b] = 0; W[b] = dis ? head[b] : -1; }
    if (!dis) return;
    int local = g2l[head[b]];
    const int* __restrict__ nb = nbs + (size_t)local * KNB;
    const float* __restrict__ w = wts + (size_t)local * KNB;
    float v0 = 0.f, v1 = 0.f;
#pragma unroll
    for (int k = 0; k < KNB; k += 2) {
        v0 = fmaf(w[k],     emb[(size_t)nb[k] * DIM + t],     v0);
        v1 = fmaf(w[k + 1], emb[(size_t)nb[k + 1] * DIM + t], v1);
    }
    vecpre[(size_t)b * DIM + t] = v0 + v1;
}

// flag[b]=1 if any OTHER disease step's write-row hits readset_b ∪ {hi_b};
// flag the writer too (symmetric) so unflagged steps are fully independent.
__global__ __launch_bounds__(256)
void conflict_kernel(const int* __restrict__ W, const int* __restrict__ head,
                     const int* __restrict__ rel, const int* __restrict__ g2l,
                     const int* __restrict__ nbs, int* __restrict__ flags) {
    int b = blockIdx.x;
    int r = rel[b];
    if (r < 4 || r > 6) return;
    __shared__ int rd[KNB + 1];
    int t = threadIdx.x;
    if (t == 0) rd[KNB] = head[b];
    if (t < KNB) {
        int local = g2l[head[b]];
        rd[t] = nbs[(size_t)local * KNB + t];
    }
    __syncthreads();
    int w = (t != b) ? W[t] : -1;
    if (w >= 0) {
        bool hit = false;
#pragma unroll
        for (int k = 0; k <= KNB; ++k) hit |= (rd[k] == w);
        if (hit) { flags[b] = 1; flags[t] = 1; }
    }
}

// apply all independent steps in parallel
__global__ __launch_bounds__(256)
void apply_par_kernel(float* __restrict__ emb, const int* __restrict__ head,
                      const int* __restrict__ rel, const float* __restrict__ cvals,
                      const float* __restrict__ vecpre, const int* __restrict__ flags) {
    int b = blockIdx.x;
    int r = rel[b];
    if (r < 4 || r > 6) return;
    if (flags[b]) return;
    int t = threadIdx.x;
    int hi = head[b];
    float c = cvals[b];
    size_t idx = (size_t)hi * DIM + t;
    emb[idx] = c * vecpre[(size_t)b * DIM + t] + (1.f - c) * emb[idx];
}

// flagged steps in program order. Each thread owns column t: every row access
// in this kernel at column t is by thread t only -> no __syncthreads needed.
__global__ __launch_bounds__(256)
void apply_seq_kernel(float* __restrict__ emb, const int* __restrict__ head,
                      const int* __restrict__ rel, const int* __restrict__ g2l,
                      const int* __restrict__ nbs, const float* __restrict__ wts,
                      const float* __restrict__ cvals, const int* __restrict__ flags) {
    __shared__ int   snb[BSZ][KNB];
    __shared__ float sw[BSZ][KNB];
    __shared__ int   sh[BSZ];
    __shared__ float sc[BSZ];
    __shared__ int   sf[BSZ];
    const int t = threadIdx.x;
    int r = rel[t];
    int dis = (r >= 4 && r <= 6);
    int hi = head[t];
    sh[t] = hi;
    sc[t] = cvals[t];
    sf[t] = dis ? flags[t] : 0;
    if (dis) {
        int local = g2l[hi];
#pragma unroll
        for (int k = 0; k < KNB; ++k) {
            snb[t][k] = nbs[(size_t)local * KNB + k];
            sw[t][k]  = wts[(size_t)local * KNB + k];
        }
    }
    __syncthreads();
    for (int b = 0; b < BSZ; ++b) {
        if (sf[b]) {
            int hh = sh[b];
            float c = sc[b];
            float v0 = 0.f, v1 = 0.f;
#pragma unroll
            for (int k = 0; k < KNB; k += 2) {
                v0 = fmaf(sw[b][k],     emb[(size_t)snb[b][k] * DIM + t],     v0);
                v1 = fmaf(sw[b][k + 1], emb[(size_t)snb[b][k + 1] * DIM + t], v1);
            }
            size_t idx = (size_t)hh * DIM + t;
            emb[idx] = c * (v0 + v1) + (1.f - c) * emb[idx];
        }
    }
}

// ------------------------------------------------------------------ decode
__global__ __launch_bounds__(256)
void decode_kernel(const float* __restrict__ emb, const int* __restrict__ head,
                   const int* __restrict__ rel, const int* __restrict__ tail,
                   const float* __restrict__ rel_emb, float* __restrict__ out) {
    int b = blockIdx.x, t = threadIdx.x;
    float v = emb[(size_t)head[b] * DIM + t] *
              rel_emb[(size_t)rel[b] * DIM + t] *
              emb[(size_t)tail[b] * DIM + t];
    __shared__ float red[4];
#pragma unroll
    for (int off = 32; off; off >>= 1) v += __shfl_down(v, off);
    int lane = t & 63, w = t >> 6;
    if (lane == 0) red[w] = v;
    __syncthreads();
    if (t == 0) {
        float s = red[0] + red[1] + red[2] + red[3];
        out[b] = 1.f / (1.f + expf(-s));
    }
}

// ------------------------------------------------------------------ launch
extern "C" void kernel_launch(void* const* d_in, const int* in_sizes, int n_in,
                              void* d_out, int out_size, void* d_ws, size_t ws_size,
                              hipStream_t stream) {
    const float* x        = (const float*)d_in[0];
    const int*   ei       = (const int*)d_in[1];
    const int*   head     = (const int*)d_in[2];
    const int*   rel      = (const int*)d_in[3];
    const int*   tail     = (const int*)d_in[4];
    const int*   g2l      = (const int*)d_in[5];
    const int*   res      = (const int*)d_in[6];
    const int*   nbs      = (const int*)d_in[7];
    const float* wts      = (const float*)d_in[8];
    const float* W1       = (const float*)d_in[9];
    const float* a1s      = (const float*)d_in[10];
    const float* a1d      = (const float*)d_in[11];
    const float* b1       = (const float*)d_in[12];
    const float* W2       = (const float*)d_in[13];
    const float* a2s      = (const float*)d_in[14];
    const float* a2d      = (const float*)d_in[15];
    const float* b2       = (const float*)d_in[16];
    const float* rel_emb  = (const float*)d_in[17];
    float* out = (float*)d_out;

    char* ws = (char*)d_ws;
    size_t off_b = 0;
    auto alloc = [&](size_t bytes) {
        void* pp = ws + off_b;
        off_b += (bytes + 255) & ~(size_t)255;
        return pp;
    };
    float* bufA    = (float*)alloc((size_t)N_NODES * DIM * 4);  // h (gemm out)
    float* bufB    = (float*)alloc((size_t)N_NODES * DIM * 4);  // layer out
    float* hs      = (float*)alloc((size_t)N_NODES * 4);
    float* hd      = (float*)alloc((size_t)N_NODES * 4);
    int*   deg     = (int*)alloc((size_t)N_NODES * 4);
    int*   offs    = (int*)alloc((size_t)(N_NODES + 1) * 4);
    int*   cnt     = (int*)alloc((size_t)N_NODES * 4);
    int*   csr_src = (int*)alloc((size_t)N_EDGES * 4);
    float* cvals   = (float*)alloc((size_t)BSZ * 4);
    float* vecpre  = (float*)alloc((size_t)BSZ * DIM * 4);
    int*   Wrows   = (int*)alloc((size_t)BSZ * 4);
    int*   flags   = (int*)alloc((size_t)BSZ * 4);

    dim3 gemmGrid((N_NODES + BM - 1) / BM, 256 / BN);
    const int edgeBlocks = (N_EDGES + 255) / 256;

    // ---------------- CSR build (graph is layer-invariant) ----------------
    hipMemsetAsync(deg, 0, (size_t)N_NODES * 4, stream);
    hipMemsetAsync(cnt, 0, (size_t)N_NODES * 4, stream);
    hist_kernel<<<edgeBlocks, 256, 0, stream>>>(ei, deg);
    scan_offsets_kernel<<<1, 256, 0, stream>>>(deg, offs);
    scatter_kernel<<<edgeBlocks, 256, 0, stream>>>(ei, offs, cnt, csr_src);

    // ---------------- layer 1 ----------------
    gemm_f32_kernel<<<gemmGrid, 256, 0, stream>>>(x, W1, bufA, N_NODES);
    node_dots_kernel<<<(N_NODES + 3) / 4, 256, 0, stream>>>(bufA, a1s, a1d, hs, hd);
    gat_aggr_kernel<<<N_NODES, 256, 0, stream>>>(offs, csr_src, hs, hd, bufA, b1, bufB, 1);

    // ---------------- layer 2 ----------------
    gemm_f32_kernel<<<gemmGrid, 256, 0, stream>>>(bufB, W2, bufA, N_NODES);
    node_dots_kernel<<<(N_NODES + 3) / 4, 256, 0, stream>>>(bufA, a2s, a2d, hs, hd);
    gat_aggr_kernel<<<N_NODES, 256, 0, stream>>>(offs, csr_src, hs, hd, bufA, b2, bufB, 0);

    // ---------------- scan (parallelized) + decode ----------------
    deg_c_kernel<<<BSZ, 256, 0, stream>>>(rel, head, g2l, res, cvals);
    prep_steps_kernel<<<BSZ, 256, 0, stream>>>(bufB, head, rel, g2l, nbs, wts,
                                               vecpre, Wrows, flags);
    conflict_kernel<<<BSZ, 256, 0, stream>>>(Wrows, head, rel, g2l, nbs, flags);
    apply_par_kernel<<<BSZ, 256, 0, stream>>>(bufB, head, rel, cvals, vecpre, flags);
    apply_seq_kernel<<<1, 256, 0, stream>>>(bufB, head, rel, g2l, nbs, wts, cvals, flags);
    decode_kernel<<<BSZ, 256, 0, stream>>>(bufB, head, rel, tail, rel_emb, out);
}

// Round 4
// 666.098 us; speedup vs baseline: 3.0035x; 1.2487x over previous
//
#include <hip/hip_runtime.h>
#include <cstdint>

#define N_NODES 50000
#define N_EDGES 800000
#define DIM     256
#define BSZ     256
#define ND_     5000
#define KNB     16
#define ER_     20000
#define LAM     0.7f

typedef unsigned int uint;
typedef unsigned short ushort;
typedef __attribute__((ext_vector_type(8))) short bf16x8;
typedef __attribute__((ext_vector_type(4))) float f32x4;

#define MTILES_PAD 3128            // ceil(50000/16) padded to multiple of 4
#define M_PAD      (MTILES_PAD*16) // 50048

__device__ __forceinline__ ushort f2bf(float f) {
    uint u = __float_as_uint(f);
    uint r = u + 0x7FFFu + ((u >> 16) & 1u);   // round-to-nearest-even
    return (ushort)(r >> 16);
}
__device__ __forceinline__ float bf2f(ushort u) {
    return __uint_as_float(((uint)u) << 16);
}

// fragment k-map: elem j, lane-group lg -> kk in [0,32)
// MUST be the same bijection for A-pack and B-pack (permutation cancels).
// kk = (j&3) + lg*4 + (j>>2)*16

// ------------------------------------- pack A [M,256] f32 -> frag-order bf16
// out[((mt*8 + kt)*64 + lane)*8 + j] = bf16(A[mt*16 + (lane&15)][kt*32 + kk])
__global__ __launch_bounds__(256)
void pack_a_kernel(const float* __restrict__ A, ushort* __restrict__ out, int M) {
    const int mt = blockIdx.x;
    const int t  = threadIdx.x;
    const int l  = t & 63;
    const int kt0 = (t >> 6) * 2;
    const int row = mt * 16 + (l & 15);
    const int lg  = l >> 4;
#pragma unroll
    for (int p = 0; p < 2; ++p) {
        int kt = kt0 + p;
        float4 v0 = make_float4(0.f, 0.f, 0.f, 0.f);
        float4 v1 = make_float4(0.f, 0.f, 0.f, 0.f);
        if (row < M) {
            v0 = *(const float4*)(A + (size_t)row * 256 + kt * 32 + lg * 4);
            v1 = *(const float4*)(A + (size_t)row * 256 + kt * 32 + lg * 4 + 16);
        }
        ushort us[8];
        us[0] = f2bf(v0.x); us[1] = f2bf(v0.y); us[2] = f2bf(v0.z); us[3] = f2bf(v0.w);
        us[4] = f2bf(v1.x); us[5] = f2bf(v1.y); us[6] = f2bf(v1.z); us[7] = f2bf(v1.w);
        ushort* dst = out + ((size_t)(mt * 8 + kt) * 64 + l) * 8;
        *(uint4*)dst = *(uint4*)us;
    }
}

// ------------------------------------- pack W [K=256,N=256] f32 -> frag order
// out[((nt*8 + kt)*64 + lane)*8 + j] = bf16(W[kt*32 + kk][nt*16 + (lane&15)])
__global__ __launch_bounds__(256)
void pack_b_kernel(const float* __restrict__ W, ushort* __restrict__ out) {
    const int nt = blockIdx.x;      // 16
    const int t  = threadIdx.x;
    const int l  = t & 63;
    const int kt0 = (t >> 6) * 2;
    const int n  = nt * 16 + (l & 15);
    const int lg = l >> 4;
#pragma unroll
    for (int p = 0; p < 2; ++p) {
        int kt = kt0 + p;
        ushort us[8];
#pragma unroll
        for (int j = 0; j < 8; ++j) {
            int kk = (j & 3) + lg * 4 + (j >> 2) * 16;
            us[j] = f2bf(W[(size_t)(kt * 32 + kk) * 256 + n]);
        }
        ushort* dst = out + ((size_t)(nt * 8 + kt) * 64 + l) * 8;
        *(uint4*)dst = *(uint4*)us;
    }
}

// ----------------------------------------------------------- bf16 MFMA GEMM
// C[M,256] = A @ B ; block = 4 waves, 64 rows; wave w -> cols [w*64, w*64+64)
__global__ __launch_bounds__(256)
void gemm_bf16_kernel(const ushort* __restrict__ Ap, const ushort* __restrict__ Bp,
                      float* __restrict__ C, int M) {
    const int w = threadIdx.x >> 6;
    const int l = threadIdx.x & 63;
    const int mt0 = blockIdx.x * 4;
    f32x4 acc[4][4];
#pragma unroll
    for (int i = 0; i < 4; ++i)
#pragma unroll
        for (int j = 0; j < 4; ++j) acc[i][j] = (f32x4){0.f, 0.f, 0.f, 0.f};

    for (int kt = 0; kt < 8; ++kt) {
        bf16x8 af[4], bfr[4];
#pragma unroll
        for (int mi = 0; mi < 4; ++mi)
            af[mi] = *(const bf16x8*)(Ap + ((size_t)((mt0 + mi) * 8 + kt) * 64 + l) * 8);
#pragma unroll
        for (int ni = 0; ni < 4; ++ni)
            bfr[ni] = *(const bf16x8*)(Bp + ((size_t)((w * 4 + ni) * 8 + kt) * 64 + l) * 8);
#pragma unroll
        for (int mi = 0; mi < 4; ++mi)
#pragma unroll
            for (int ni = 0; ni < 4; ++ni)
                acc[mi][ni] = __builtin_amdgcn_mfma_f32_16x16x32_bf16(
                    af[mi], bfr[ni], acc[mi][ni], 0, 0, 0);
    }
    const int rbase = (l >> 4) * 4;   // C/D: col=lane&15, row=(lane>>4)*4+reg  [m89/m91]
    const int cb    = (l & 15);
#pragma unroll
    for (int mi = 0; mi < 4; ++mi) {
        int row0 = (mt0 + mi) * 16 + rbase;
#pragma unroll
        for (int r = 0; r < 4; ++r) {
            int row = row0 + r;
            if (row < M) {
#pragma unroll
                for (int ni = 0; ni < 4; ++ni) {
                    int col = (w * 4 + ni) * 16 + cb;
                    C[(size_t)row * 256 + col] = acc[mi][ni][r];
                }
            }
        }
    }
}

// ------------------------- per-node attention dots (+ bf16 row-major copy)
__global__ __launch_bounds__(256)
void node_dots_kernel(const float* __restrict__ h,
                      const float* __restrict__ a_src,
                      const float* __restrict__ a_dst,
                      float* __restrict__ hs, float* __restrict__ hd,
                      ushort* __restrict__ hb) {
    int node = blockIdx.x * 4 + (threadIdx.x >> 6);
    int lane = threadIdx.x & 63;
    if (node >= N_NODES) return;
    float4 v  = ((const float4*)(h + (size_t)node * DIM))[lane];
    float4 as = ((const float4*)a_src)[lane];
    float4 ad = ((const float4*)a_dst)[lane];
    // bf16 copy for the aggregation gather
    ushort us[4] = {f2bf(v.x), f2bf(v.y), f2bf(v.z), f2bf(v.w)};
    *(uint2*)(hb + (size_t)node * DIM + lane * 4) = *(uint2*)us;
    float ssum = v.x * as.x + v.y * as.y + v.z * as.z + v.w * as.w;
    float dsum = v.x * ad.x + v.y * ad.y + v.z * ad.z + v.w * ad.w;
#pragma unroll
    for (int off = 32; off; off >>= 1) {
        ssum += __shfl_down(ssum, off);
        dsum += __shfl_down(dsum, off);
    }
    if (lane == 0) { hs[node] = ssum; hd[node] = dsum; }
}

// -------------------------------------------------------------- CSR build
__global__ __launch_bounds__(256)
void hist_kernel(const int* __restrict__ ei, int* __restrict__ deg) {
    int e = blockIdx.x * 256 + threadIdx.x;
    if (e < N_EDGES) atomicAdd(&deg[ei[N_EDGES + e]], 1);
}

__global__ __launch_bounds__(256)
void scan_offsets_kernel(const int* __restrict__ deg, int* __restrict__ off) {
    __shared__ int sums[256];
    const int t = threadIdx.x;
    const int CH = (N_NODES + 255) / 256;   // 196
    int b0 = t * CH;
    int s = 0;
    for (int i = 0; i < CH; ++i) {
        int idx = b0 + i;
        if (idx < N_NODES) s += deg[idx];
    }
    sums[t] = s;
    __syncthreads();
    for (int o = 1; o < 256; o <<= 1) {
        int v = (t >= o) ? sums[t - o] : 0;
        __syncthreads();
        sums[t] += v;
        __syncthreads();
    }
    int prefix = (t == 0) ? 0 : sums[t - 1];
    for (int i = 0; i < CH; ++i) {
        int idx = b0 + i;
        if (idx < N_NODES) { off[idx] = prefix; prefix += deg[idx]; }
    }
    if (t == 255) off[N_NODES] = sums[255];
}

__global__ __launch_bounds__(256)
void scatter_kernel(const int* __restrict__ ei, const int* __restrict__ off,
                    int* __restrict__ cnt, int* __restrict__ csr_src) {
    int e = blockIdx.x * 256 + threadIdx.x;
    if (e >= N_EDGES) return;
    int d = ei[N_EDGES + e];
    int pos = atomicAdd(&cnt[d], 1);
    csr_src[off[d] + pos] = ei[e];
}

// --------------------------- fused GAT edge stage (gather form, bf16 rows)
#define CAP 256
__global__ __launch_bounds__(256)
void gat_aggr_kernel(const int* __restrict__ off, const int* __restrict__ csr_src,
                     const float* __restrict__ hs, const float* __restrict__ hd,
                     const ushort* __restrict__ hb, const float* __restrict__ bias,
                     float* __restrict__ outbuf, int do_silu) {
    const int d = blockIdx.x;
    const int t = threadIdx.x;
    const int beg = off[d], end = off[d + 1];
    __shared__ float pv[CAP];
    __shared__ int   ss[CAP];
    __shared__ float red[4];

    float acc = 0.f;
    float m = -1e30f, z = 0.f;
    const float hdd = hd[d];
    const ushort* __restrict__ hcol = hb + t;

    for (int c0 = beg; c0 < end; c0 += CAP) {
        const int cn = min(end - c0, CAP);
        if (t < cn) {
            int s = csr_src[c0 + t];
            ss[t] = s;
            float v = hs[s] + hdd;
            pv[t] = (v >= 0.f) ? v : 0.2f * v;
        }
        __syncthreads();
        float lm = (t < cn) ? pv[t] : -1e30f;
#pragma unroll
        for (int o = 32; o; o >>= 1) lm = fmaxf(lm, __shfl_down(lm, o));
        if ((t & 63) == 0) red[t >> 6] = lm;
        __syncthreads();
        float cmax = fmaxf(fmaxf(red[0], red[1]), fmaxf(red[2], red[3]));
        float mn = fmaxf(m, cmax);
        float scale = __expf(m - mn);
        z *= scale; acc *= scale;
        __syncthreads();
        if (t < cn) pv[t] = __expf(pv[t] - mn);
        __syncthreads();
        float lz = (t < cn) ? pv[t] : 0.f;
#pragma unroll
        for (int o = 32; o; o >>= 1) lz += __shfl_down(lz, o);
        if ((t & 63) == 0) red[t >> 6] = lz;
        __syncthreads();
        z += red[0] + red[1] + red[2] + red[3];
        float a0 = 0.f, a1 = 0.f, a2 = 0.f, a3 = 0.f;
        int j = 0;
        for (; j + 4 <= cn; j += 4) {
            a0 = fmaf(pv[j + 0], bf2f(hcol[(size_t)ss[j + 0] * DIM]), a0);
            a1 = fmaf(pv[j + 1], bf2f(hcol[(size_t)ss[j + 1] * DIM]), a1);
            a2 = fmaf(pv[j + 2], bf2f(hcol[(size_t)ss[j + 2] * DIM]), a2);
            a3 = fmaf(pv[j + 3], bf2f(hcol[(size_t)ss[j + 3] * DIM]), a3);
        }
        for (; j < cn; ++j)
            a0 = fmaf(pv[j], bf2f(hcol[(size_t)ss[j] * DIM]), a0);
        acc += (a0 + a1) + (a2 + a3);
        __syncthreads();
        m = mn;
    }
    float o = (end > beg) ? acc / (z + 1e-16f) : 0.f;
    o += bias[t];
    if (do_silu) o = o / (1.f + __expf(-o));
    outbuf[(size_t)d * DIM + t] = o;
}

// --------------------------------------------- precompute c[b] (deg counting)
__global__ __launch_bounds__(256)
void deg_c_kernel(const int* __restrict__ rel, const int* __restrict__ head,
                  const int* __restrict__ g2l, const int* __restrict__ res,
                  float* __restrict__ cvals) {
    int b = blockIdx.x;
    int r = rel[b];
    if (r < 4 || r > 6) { if (threadIdx.x == 0) cvals[b] = 0.f; return; }
    int local = g2l[head[b]];
    const int* rr = res + (size_t)(r - 4) * ER_;
    int cnt = 0;
    for (int i = threadIdx.x; i < ER_; i += 256) cnt += (rr[i] == local);
    __shared__ int sdeg;
    if (threadIdx.x == 0) sdeg = 0;
    __syncthreads();
#pragma unroll
    for (int off = 32; off; off >>= 1) cnt += __shfl_down(cnt, off);
    if ((threadIdx.x & 63) == 0) atomicAdd(&sdeg, cnt);
    __syncthreads();
    if (threadIdx.x == 0)
        cvals[b] = LAM * expf(-LAM * (float)sdeg) + 0.2f;
}

// -------------------------- parallelized sequential scan -------------------
__global__ __launch_bounds__(256)
void prep_steps_kernel(const float* __restrict__ emb, const int* __restrict__ head,
                       const int* __restrict__ rel, const int* __restrict__ g2l,
                       const int* __restrict__ nbs, const float* __restrict__ wts,
                       float* __restrict__ vecpre, int* __restrict__ W,
                       int* __restrict__ flags) {
    int b = blockIdx.x;
    int t = threadIdx.x;
    int r = rel[b];
    int dis = (r >= 4 && r <= 6);
    if (t == 0) { flags[b] = 0; W[b] = dis ? head[b] : -1; }
    if (!dis) return;
    int local = g2l[head[b]];
    const int* __restrict__ nb = nbs + (size_t)local * KNB;
    const float* __restrict__ w = wts + (size_t)local * KNB;
    float v0 = 0.f, v1 = 0.f;
#pragma unroll
    for (int k = 0; k < KNB; k += 2) {
        v0 = fmaf(w[k],     emb[(size_t)nb[k] * DIM + t],     v0);
        v1 = fmaf(w[k + 1], emb[(size_t)nb[k + 1] * DIM + t], v1);
    }
    vecpre[(size_t)b * DIM + t] = v0 + v1;
}

__global__ __launch_bounds__(256)
void conflict_kernel(const int* __restrict__ W, const int* __restrict__ head,
                     const int* __restrict__ rel, const int* __restrict__ g2l,
                     const int* __restrict__ nbs, int* __restrict__ flags) {
    int b = blockIdx.x;
    int r = rel[b];
    if (r < 4 || r > 6) return;
    __shared__ int rd[KNB + 1];
    int t = threadIdx.x;
    if (t == 0) rd[KNB] = head[b];
    if (t < KNB) {
        int local = g2l[head[b]];
        rd[t] = nbs[(size_t)local * KNB + t];
    }
    __syncthreads();
    int w = (t != b) ? W[t] : -1;
    if (w >= 0) {
        bool hit = false;
#pragma unroll
        for (int k = 0; k <= KNB; ++k) hit |= (rd[k] == w);
        if (hit) { flags[b] = 1; flags[t] = 1; }
    }
}

__global__ __launch_bounds__(256)
void apply_par_kernel(float* __restrict__ emb, const int* __restrict__ head,
                      const int* __restrict__ rel, const float* __restrict__ cvals,
                      const float* __restrict__ vecpre, const int* __restrict__ flags) {
    int b = blockIdx.x;
    int r = rel[b];
    if (r < 4 || r > 6) return;
    if (flags[b]) return;
    int t = threadIdx.x;
    int hi = head[b];
    float c = cvals[b];
    size_t idx = (size_t)hi * DIM + t;
    emb[idx] = c * vecpre[(size_t)b * DIM + t] + (1.f - c) * emb[idx];
}

__global__ __launch_bounds__(256)
void apply_seq_kernel(float* __restrict__ emb, const int* __restrict__ head,
                      const int* __restrict__ rel, const int* __restrict__ g2l,
                      const int* __restrict__ nbs, const float* __restrict__ wts,
                      const float* __restrict__ cvals, const int* __restrict__ flags) {
    __shared__ int   snb[BSZ][KNB];
    __shared__ float sw[BSZ][KNB];
    __shared__ int   sh[BSZ];
    __shared__ float sc[BSZ];
    __shared__ int   sf[BSZ];
    const int t = threadIdx.x;
    int r = rel[t];
    int dis = (r >= 4 && r <= 6);
    int hi = head[t];
    sh[t] = hi;
    sc[t] = cvals[t];
    sf[t] = dis ? flags[t] : 0;
    if (dis) {
        int local = g2l[hi];
#pragma unroll
        for (int k = 0; k < KNB; ++k) {
            snb[t][k] = nbs[(size_t)local * KNB + k];
            sw[t][k]  = wts[(size_t)local * KNB + k];
        }
    }
    __syncthreads();
    for (int b = 0; b < BSZ; ++b) {
        if (sf[b]) {
            int hh = sh[b];
            float c = sc[b];
            float v0 = 0.f, v1 = 0.f;
#pragma unroll
            for (int k = 0; k < KNB; k += 2) {
                v0 = fmaf(sw[b][k],     emb[(size_t)snb[b][k] * DIM + t],     v0);
                v1 = fmaf(sw[b][k + 1], emb[(size_t)snb[b][k + 1] * DIM + t], v1);
            }
            size_t idx = (size_t)hh * DIM + t;
            emb[idx] = c * (v0 + v1) + (1.f - c) * emb[idx];
        }
    }
}

// ------------------------------------------------------------------ decode
__global__ __launch_bounds__(256)
void decode_kernel(const float* __restrict__ emb, const int* __restrict__ head,
                   const int* __restrict__ rel, const int* __restrict__ tail,
                   const float* __restrict__ rel_emb, float* __restrict__ out) {
    int b = blockIdx.x, t = threadIdx.x;
    float v = emb[(size_t)head[b] * DIM + t] *
              rel_emb[(size_t)rel[b] * DIM + t] *
              emb[(size_t)tail[b] * DIM + t];
    __shared__ float red[4];
#pragma unroll
    for (int off = 32; off; off >>= 1) v += __shfl_down(v, off);
    int lane = t & 63, w = t >> 6;
    if (lane == 0) red[w] = v;
    __syncthreads();
    if (t == 0) {
        float s = red[0] + red[1] + red[2] + red[3];
        out[b] = 1.f / (1.f + expf(-s));
    }
}

// ------------------------------------------------------------------ launch
extern "C" void kernel_launch(void* const* d_in, const int* in_sizes, int n_in,
                              void* d_out, int out_size, void* d_ws, size_t ws_size,
                              hipStream_t stream) {
    const float* x        = (const float*)d_in[0];
    const int*   ei       = (const int*)d_in[1];
    const int*   head     = (const int*)d_in[2];
    const int*   rel      = (const int*)d_in[3];
    const int*   tail     = (const int*)d_in[4];
    const int*   g2l      = (const int*)d_in[5];
    const int*   res      = (const int*)d_in[6];
    const int*   nbs      = (const int*)d_in[7];
    const float* wts      = (const float*)d_in[8];
    const float* W1       = (const float*)d_in[9];
    const float* a1s      = (const float*)d_in[10];
    const float* a1d      = (const float*)d_in[11];
    const float* b1       = (const float*)d_in[12];
    const float* W2       = (const float*)d_in[13];
    const float* a2s      = (const float*)d_in[14];
    const float* a2d      = (const float*)d_in[15];
    const float* b2       = (const float*)d_in[16];
    const float* rel_emb  = (const float*)d_in[17];
    float* out = (float*)d_out;

    char* ws = (char*)d_ws;
    size_t off_b = 0;
    auto alloc = [&](size_t bytes) {
        void* pp = ws + off_b;
        off_b += (bytes + 255) & ~(size_t)255;
        return pp;
    };
    float*  bufA    = (float*)alloc((size_t)N_NODES * DIM * 4);  // h (gemm out)
    float*  bufB    = (float*)alloc((size_t)N_NODES * DIM * 4);  // layer out
    float*  hs      = (float*)alloc((size_t)N_NODES * 4);
    float*  hd      = (float*)alloc((size_t)N_NODES * 4);
    int*    deg     = (int*)alloc((size_t)N_NODES * 4);
    int*    offs    = (int*)alloc((size_t)(N_NODES + 1) * 4);
    int*    cnt     = (int*)alloc((size_t)N_NODES * 4);
    int*    csr_src = (int*)alloc((size_t)N_EDGES * 4);
    float*  cvals   = (float*)alloc((size_t)BSZ * 4);
    float*  vecpre  = (float*)alloc((size_t)BSZ * DIM * 4);
    int*    Wrows   = (int*)alloc((size_t)BSZ * 4);
    int*    flags   = (int*)alloc((size_t)BSZ * 4);
    ushort* apack   = (ushort*)alloc((size_t)M_PAD * 256 * 2);   // xb / h1 pack (reused)
    ushort* hb      = (ushort*)alloc((size_t)N_NODES * DIM * 2); // bf16 h rows
    ushort* wpack1  = (ushort*)alloc((size_t)256 * 256 * 2);
    ushort* wpack2  = (ushort*)alloc((size_t)256 * 256 * 2);

    const int edgeBlocks = (N_EDGES + 255) / 256;
    const int gemmBlocks = MTILES_PAD / 4;   // 782

    // ---------------- CSR build + weight packs (graph/W layer-invariant) ----
    hipMemsetAsync(deg, 0, (size_t)N_NODES * 4, stream);
    hipMemsetAsync(cnt, 0, (size_t)N_NODES * 4, stream);
    hist_kernel<<<edgeBlocks, 256, 0, stream>>>(ei, deg);
    scan_offsets_kernel<<<1, 256, 0, stream>>>(deg, offs);
    scatter_kernel<<<edgeBlocks, 256, 0, stream>>>(ei, offs, cnt, csr_src);
    pack_b_kernel<<<16, 256, 0, stream>>>(W1, wpack1);
    pack_b_kernel<<<16, 256, 0, stream>>>(W2, wpack2);

    // ---------------- layer 1 ----------------
    pack_a_kernel<<<MTILES_PAD, 256, 0, stream>>>(x, apack, N_NODES);
    gemm_bf16_kernel<<<gemmBlocks, 256, 0, stream>>>(apack, wpack1, bufA, N_NODES);
    node_dots_kernel<<<(N_NODES + 3) / 4, 256, 0, stream>>>(bufA, a1s, a1d, hs, hd, hb);
    gat_aggr_kernel<<<N_NODES, 256, 0, stream>>>(offs, csr_src, hs, hd, hb, b1, bufB, 1);

    // ---------------- layer 2 ----------------
    pack_a_kernel<<<MTILES_PAD, 256, 0, stream>>>(bufB, apack, N_NODES);
    gemm_bf16_kernel<<<gemmBlocks, 256, 0, stream>>>(apack, wpack2, bufA, N_NODES);
    node_dots_kernel<<<(N_NODES + 3) / 4, 256, 0, stream>>>(bufA, a2s, a2d, hs, hd, hb);
    gat_aggr_kernel<<<N_NODES, 256, 0, stream>>>(offs, csr_src, hs, hd, hb, b2, bufB, 0);

    // ---------------- scan (parallelized) + decode ----------------
    deg_c_kernel<<<BSZ, 256, 0, stream>>>(rel, head, g2l, res, cvals);
    prep_steps_kernel<<<BSZ, 256, 0, stream>>>(bufB, head, rel, g2l, nbs, wts,
                                               vecpre, Wrows, flags);
    conflict_kernel<<<BSZ, 256, 0, stream>>>(Wrows, head, rel, g2l, nbs, flags);
    apply_par_kernel<<<BSZ, 256, 0, stream>>>(bufB, head, rel, cvals, vecpre, flags);
    apply_seq_kernel<<<1, 256, 0, stream>>>(bufB, head, rel, g2l, nbs, wts, cvals, flags);
    decode_kernel<<<BSZ, 256, 0, stream>>>(bufB, head, rel, tail, rel_emb, out);
}

// Round 5
// 569.928 us; speedup vs baseline: 3.5104x; 1.1687x over previous
//
#include <hip/hip_runtime.h>
#include <cstdint>

#define N_NODES 50000
#define N_EDGES 800000
#define DIM     256
#define BSZ     256
#define ND_     5000
#define KNB     16
#define ER_     20000
#define LAM     0.7f

typedef unsigned int uint;
typedef unsigned short ushort;
typedef __attribute__((ext_vector_type(8))) short bf16x8;
typedef __attribute__((ext_vector_type(4))) float f32x4;

#define MTILES_PAD 3128            // ceil(50000/16) padded to multiple of 4
#define M_PAD      (MTILES_PAD*16) // 50048

__device__ __forceinline__ ushort f2bf(float f) {
    uint u = __float_as_uint(f);
    uint r = u + 0x7FFFu + ((u >> 16) & 1u);   // round-to-nearest-even
    return (ushort)(r >> 16);
}
__device__ __forceinline__ float bf2f(ushort u) {
    return __uint_as_float(((uint)u) << 16);
}

// fragment k-map: elem j, lane-group lg -> kk in [0,32)
// same bijection for A-pack and B-pack (permutation cancels): kk=(j&3)+lg*4+(j>>2)*16

// ------------------------------------- pack A [M,256] f32 -> frag-order bf16
__global__ __launch_bounds__(256)
void pack_a_kernel(const float* __restrict__ A, ushort* __restrict__ out, int M) {
    const int mt = blockIdx.x;
    const int t  = threadIdx.x;
    const int l  = t & 63;
    const int kt0 = (t >> 6) * 2;
    const int row = mt * 16 + (l & 15);
    const int lg  = l >> 4;
#pragma unroll
    for (int p = 0; p < 2; ++p) {
        int kt = kt0 + p;
        float4 v0 = make_float4(0.f, 0.f, 0.f, 0.f);
        float4 v1 = make_float4(0.f, 0.f, 0.f, 0.f);
        if (row < M) {
            v0 = *(const float4*)(A + (size_t)row * 256 + kt * 32 + lg * 4);
            v1 = *(const float4*)(A + (size_t)row * 256 + kt * 32 + lg * 4 + 16);
        }
        ushort us[8];
        us[0] = f2bf(v0.x); us[1] = f2bf(v0.y); us[2] = f2bf(v0.z); us[3] = f2bf(v0.w);
        us[4] = f2bf(v1.x); us[5] = f2bf(v1.y); us[6] = f2bf(v1.z); us[7] = f2bf(v1.w);
        ushort* dst = out + ((size_t)(mt * 8 + kt) * 64 + l) * 8;
        *(uint4*)dst = *(uint4*)us;
    }
}

// ------------------------------------- pack W [K=256,N=256] f32 -> frag order
__global__ __launch_bounds__(256)
void pack_b_kernel(const float* __restrict__ W, ushort* __restrict__ out) {
    const int nt = blockIdx.x;      // 16
    const int t  = threadIdx.x;
    const int l  = t & 63;
    const int kt0 = (t >> 6) * 2;
    const int n  = nt * 16 + (l & 15);
    const int lg = l >> 4;
#pragma unroll
    for (int p = 0; p < 2; ++p) {
        int kt = kt0 + p;
        ushort us[8];
#pragma unroll
        for (int j = 0; j < 8; ++j) {
            int kk = (j & 3) + lg * 4 + (j >> 2) * 16;
            us[j] = f2bf(W[(size_t)(kt * 32 + kk) * 256 + n]);
        }
        ushort* dst = out + ((size_t)(nt * 8 + kt) * 64 + l) * 8;
        *(uint4*)dst = *(uint4*)us;
    }
}

// ----------------------------------------------------------- bf16 MFMA GEMM
// H[M,256] (bf16 row-major) = A @ B ; block = 4 waves, 64 rows
__global__ __launch_bounds__(256)
void gemm_bf16_kernel(const ushort* __restrict__ Ap, const ushort* __restrict__ Bp,
                      ushort* __restrict__ H, int M) {
    const int w = threadIdx.x >> 6;
    const int l = threadIdx.x & 63;
    const int mt0 = blockIdx.x * 4;
    f32x4 acc[4][4];
#pragma unroll
    for (int i = 0; i < 4; ++i)
#pragma unroll
        for (int j = 0; j < 4; ++j) acc[i][j] = (f32x4){0.f, 0.f, 0.f, 0.f};

    for (int kt = 0; kt < 8; ++kt) {
        bf16x8 af[4], bfr[4];
#pragma unroll
        for (int mi = 0; mi < 4; ++mi)
            af[mi] = *(const bf16x8*)(Ap + ((size_t)((mt0 + mi) * 8 + kt) * 64 + l) * 8);
#pragma unroll
        for (int ni = 0; ni < 4; ++ni)
            bfr[ni] = *(const bf16x8*)(Bp + ((size_t)((w * 4 + ni) * 8 + kt) * 64 + l) * 8);
#pragma unroll
        for (int mi = 0; mi < 4; ++mi)
#pragma unroll
            for (int ni = 0; ni < 4; ++ni)
                acc[mi][ni] = __builtin_amdgcn_mfma_f32_16x16x32_bf16(
                    af[mi], bfr[ni], acc[mi][ni], 0, 0, 0);
    }
    const int rbase = (l >> 4) * 4;   // C/D: col=lane&15, row=(lane>>4)*4+reg  [m89/m91]
    const int cb    = (l & 15);
#pragma unroll
    for (int mi = 0; mi < 4; ++mi) {
        int row0 = (mt0 + mi) * 16 + rbase;
#pragma unroll
        for (int r = 0; r < 4; ++r) {
            int row = row0 + r;
            if (row < M) {
#pragma unroll
                for (int ni = 0; ni < 4; ++ni) {
                    int col = (w * 4 + ni) * 16 + cb;
                    H[(size_t)row * 256 + col] = f2bf(acc[mi][ni][r]);
                }
            }
        }
    }
}

// ------------------------- per-node attention dots (bf16 rows in)
__global__ __launch_bounds__(256)
void node_dots_kernel(const ushort* __restrict__ hb,
                      const float* __restrict__ a_src,
                      const float* __restrict__ a_dst,
                      float* __restrict__ hs, float* __restrict__ hd) {
    int node = blockIdx.x * 4 + (threadIdx.x >> 6);
    int lane = threadIdx.x & 63;
    if (node >= N_NODES) return;
    uint2 rv = *(const uint2*)(hb + (size_t)node * DIM + lane * 4);
    float f0 = __uint_as_float(rv.x << 16);
    float f1 = __uint_as_float(rv.x & 0xffff0000u);
    float f2 = __uint_as_float(rv.y << 16);
    float f3 = __uint_as_float(rv.y & 0xffff0000u);
    float4 as = ((const float4*)a_src)[lane];
    float4 ad = ((const float4*)a_dst)[lane];
    float ssum = f0 * as.x + f1 * as.y + f2 * as.z + f3 * as.w;
    float dsum = f0 * ad.x + f1 * ad.y + f2 * ad.z + f3 * ad.w;
#pragma unroll
    for (int off = 32; off; off >>= 1) {
        ssum += __shfl_down(ssum, off);
        dsum += __shfl_down(dsum, off);
    }
    if (lane == 0) { hs[node] = ssum; hd[node] = dsum; }
}

// -------------------------------------------------------------- CSR build
__global__ __launch_bounds__(256)
void hist_kernel(const int* __restrict__ ei, int* __restrict__ deg) {
    int e = blockIdx.x * 256 + threadIdx.x;
    if (e < N_EDGES) atomicAdd(&deg[ei[N_EDGES + e]], 1);
}

__global__ __launch_bounds__(256)
void scan_offsets_kernel(const int* __restrict__ deg, int* __restrict__ off) {
    __shared__ int sums[256];
    const int t = threadIdx.x;
    const int CH = (N_NODES + 255) / 256;   // 196
    int b0 = t * CH;
    int s = 0;
    for (int i = 0; i < CH; ++i) {
        int idx = b0 + i;
        if (idx < N_NODES) s += deg[idx];
    }
    sums[t] = s;
    __syncthreads();
    for (int o = 1; o < 256; o <<= 1) {
        int v = (t >= o) ? sums[t - o] : 0;
        __syncthreads();
        sums[t] += v;
        __syncthreads();
    }
    int prefix = (t == 0) ? 0 : sums[t - 1];
    for (int i = 0; i < CH; ++i) {
        int idx = b0 + i;
        if (idx < N_NODES) { off[idx] = prefix; prefix += deg[idx]; }
    }
    if (t == 255) off[N_NODES] = sums[255];
}

__global__ __launch_bounds__(256)
void scatter_kernel(const int* __restrict__ ei, const int* __restrict__ off,
                    int* __restrict__ cnt, int* __restrict__ csr_src) {
    int e = blockIdx.x * 256 + threadIdx.x;
    if (e >= N_EDGES) return;
    int d = ei[N_EDGES + e];
    int pos = atomicAdd(&cnt[d], 1);
    csr_src[off[d] + pos] = ei[e];
}

// ----------------- fused GAT edge stage: wave-per-dst, no max, no barriers
// softmax shift-invariance: alpha = exp(e)/sum(exp(e)); |e| <= ~10 so safe.
__global__ __launch_bounds__(256)
void gat_aggr_kernel(const int* __restrict__ off, const int* __restrict__ csr_src,
                     const float* __restrict__ hs, const float* __restrict__ hd,
                     const ushort* __restrict__ hb, const float* __restrict__ bias,
                     float* __restrict__ outbuf, int do_silu) {
    const int d = blockIdx.x * 4 + (threadIdx.x >> 6);
    const int l = threadIdx.x & 63;
    if (d >= N_NODES) return;
    const int beg = off[d], end = off[d + 1];
    const float hdd = hd[d];

    float acc0 = 0.f, acc1 = 0.f, acc2 = 0.f, acc3 = 0.f;
    float zl = 0.f;

    for (int c0 = beg; c0 < end; c0 += 64) {
        const int cn = min(end - c0, 64);
        int s = 0; float pexp = 0.f;
        if (l < cn) {
            s = csr_src[c0 + l];
            float v = hs[s] + hdd;
            v = (v >= 0.f) ? v : 0.2f * v;
            pexp = __expf(v);
        }
        zl += pexp;
        for (int j = 0; j < cn; ++j) {
            int   sj = __shfl(s, j);       // uniform j -> readlane
            float pj = __shfl(pexp, j);
            uint2 rv = *(const uint2*)(hb + (size_t)sj * DIM + l * 4);
            acc0 = fmaf(pj, __uint_as_float(rv.x << 16),          acc0);
            acc1 = fmaf(pj, __uint_as_float(rv.x & 0xffff0000u),  acc1);
            acc2 = fmaf(pj, __uint_as_float(rv.y << 16),          acc2);
            acc3 = fmaf(pj, __uint_as_float(rv.y & 0xffff0000u),  acc3);
        }
    }
    float z = zl;
#pragma unroll
    for (int o = 32; o; o >>= 1) z += __shfl_xor(z, o);
    const float inv = (end > beg) ? 1.f / (z + 1e-16f) : 0.f;
    float4 bb = *(const float4*)(bias + l * 4);
    float o0 = acc0 * inv + bb.x;
    float o1 = acc1 * inv + bb.y;
    float o2 = acc2 * inv + bb.z;
    float o3 = acc3 * inv + bb.w;
    if (do_silu) {
        o0 = o0 / (1.f + __expf(-o0));
        o1 = o1 / (1.f + __expf(-o1));
        o2 = o2 / (1.f + __expf(-o2));
        o3 = o3 / (1.f + __expf(-o3));
    }
    *(float4*)(outbuf + (size_t)d * DIM + l * 4) = make_float4(o0, o1, o2, o3);
}

// --------------------------------------------- precompute c[b] (deg counting)
__global__ __launch_bounds__(256)
void deg_c_kernel(const int* __restrict__ rel, const int* __restrict__ head,
                  const int* __restrict__ g2l, const int* __restrict__ res,
                  float* __restrict__ cvals) {
    int b = blockIdx.x;
    int r = rel[b];
    if (r < 4 || r > 6) { if (threadIdx.x == 0) cvals[b] = 0.f; return; }
    int local = g2l[head[b]];
    const int* rr = res + (size_t)(r - 4) * ER_;
    int cnt = 0;
    for (int i = threadIdx.x; i < ER_; i += 256) cnt += (rr[i] == local);
    __shared__ int sdeg;
    if (threadIdx.x == 0) sdeg = 0;
    __syncthreads();
#pragma unroll
    for (int off = 32; off; off >>= 1) cnt += __shfl_down(cnt, off);
    if ((threadIdx.x & 63) == 0) atomicAdd(&sdeg, cnt);
    __syncthreads();
    if (threadIdx.x == 0)
        cvals[b] = LAM * expf(-LAM * (float)sdeg) + 0.2f;
}

// -------------------------- parallelized sequential scan -------------------
__global__ __launch_bounds__(256)
void prep_steps_kernel(const float* __restrict__ emb, const int* __restrict__ head,
                       const int* __restrict__ rel, const int* __restrict__ g2l,
                       const int* __restrict__ nbs, const float* __restrict__ wts,
                       float* __restrict__ vecpre, int* __restrict__ W,
                       int* __restrict__ flags) {
    int b = blockIdx.x;
    int t = threadIdx.x;
    int r = rel[b];
    int dis = (r >= 4 && r <= 6);
    if (t == 0) { flags[b] = 0; W[b] = dis ? head[b] : -1; }
    if (!dis) return;
    int local = g2l[head[b]];
    const int* __restrict__ nb = nbs + (size_t)local * KNB;
    const float* __restrict__ w = wts + (size_t)local * KNB;
    float v0 = 0.f, v1 = 0.f;
#pragma unroll
    for (int k = 0; k < KNB; k += 2) {
        v0 = fmaf(w[k],     emb[(size_t)nb[k] * DIM + t],     v0);
        v1 = fmaf(w[k + 1], emb[(size_t)nb[k + 1] * DIM + t], v1);
    }
    vecpre[(size_t)b * DIM + t] = v0 + v1;
}

__global__ __launch_bounds__(256)
void conflict_kernel(const int* __restrict__ W, const int* __restrict__ head,
                     const int* __restrict__ rel, const int* __restrict__ g2l,
                     const int* __restrict__ nbs, int* __restrict__ flags) {
    int b = blockIdx.x;
    int r = rel[b];
    if (r < 4 || r > 6) return;
    __shared__ int rd[KNB + 1];
    int t = threadIdx.x;
    if (t == 0) rd[KNB] = head[b];
    if (t < KNB) {
        int local = g2l[head[b]];
        rd[t] = nbs[(size_t)local * KNB + t];
    }
    __syncthreads();
    int w = (t != b) ? W[t] : -1;
    if (w >= 0) {
        bool hit = false;
#pragma unroll
        for (int k = 0; k <= KNB; ++k) hit |= (rd[k] == w);
        if (hit) { flags[b] = 1; flags[t] = 1; }
    }
}

__global__ __launch_bounds__(256)
void apply_par_kernel(float* __restrict__ emb, const int* __restrict__ head,
                      const int* __restrict__ rel, const float* __restrict__ cvals,
                      const float* __restrict__ vecpre, const int* __restrict__ flags) {
    int b = blockIdx.x;
    int r = rel[b];
    if (r < 4 || r > 6) return;
    if (flags[b]) return;
    int t = threadIdx.x;
    int hi = head[b];
    float c = cvals[b];
    size_t idx = (size_t)hi * DIM + t;
    emb[idx] = c * vecpre[(size_t)b * DIM + t] + (1.f - c) * emb[idx];
}

__global__ __launch_bounds__(256)
void apply_seq_kernel(float* __restrict__ emb, const int* __restrict__ head,
                      const int* __restrict__ rel, const int* __restrict__ g2l,
                      const int* __restrict__ nbs, const float* __restrict__ wts,
                      const float* __restrict__ cvals, const int* __restrict__ flags) {
    __shared__ int   snb[BSZ][KNB];
    __shared__ float sw[BSZ][KNB];
    __shared__ int   sh[BSZ];
    __shared__ float sc[BSZ];
    __shared__ int   sf[BSZ];
    const int t = threadIdx.x;
    int r = rel[t];
    int dis = (r >= 4 && r <= 6);
    int hi = head[t];
    sh[t] = hi;
    sc[t] = cvals[t];
    sf[t] = dis ? flags[t] : 0;
    if (dis) {
        int local = g2l[hi];
#pragma unroll
        for (int k = 0; k < KNB; ++k) {
            snb[t][k] = nbs[(size_t)local * KNB + k];
            sw[t][k]  = wts[(size_t)local * KNB + k];
        }
    }
    __syncthreads();
    for (int b = 0; b < BSZ; ++b) {
        if (sf[b]) {
            int hh = sh[b];
            float c = sc[b];
            float v0 = 0.f, v1 = 0.f;
#pragma unroll
            for (int k = 0; k < KNB; k += 2) {
                v0 = fmaf(sw[b][k],     emb[(size_t)snb[b][k] * DIM + t],     v0);
                v1 = fmaf(sw[b][k + 1], emb[(size_t)snb[b][k + 1] * DIM + t], v1);
            }
            size_t idx = (size_t)hh * DIM + t;
            emb[idx] = c * (v0 + v1) + (1.f - c) * emb[idx];
        }
    }
}

// ------------------------------------------------------------------ decode
__global__ __launch_bounds__(256)
void decode_kernel(const float* __restrict__ emb, const int* __restrict__ head,
                   const int* __restrict__ rel, const int* __restrict__ tail,
                   const float* __restrict__ rel_emb, float* __restrict__ out) {
    int b = blockIdx.x, t = threadIdx.x;
    float v = emb[(size_t)head[b] * DIM + t] *
              rel_emb[(size_t)rel[b] * DIM + t] *
              emb[(size_t)tail[b] * DIM + t];
    __shared__ float red[4];
#pragma unroll
    for (int off = 32; off; off >>= 1) v += __shfl_down(v, off);
    int lane = t & 63, w = t >> 6;
    if (lane == 0) red[w] = v;
    __syncthreads();
    if (t == 0) {
        float s = red[0] + red[1] + red[2] + red[3];
        out[b] = 1.f / (1.f + expf(-s));
    }
}

// ------------------------------------------------------------------ launch
extern "C" void kernel_launch(void* const* d_in, const int* in_sizes, int n_in,
                              void* d_out, int out_size, void* d_ws, size_t ws_size,
                              hipStream_t stream) {
    const float* x        = (const float*)d_in[0];
    const int*   ei       = (const int*)d_in[1];
    const int*   head     = (const int*)d_in[2];
    const int*   rel      = (const int*)d_in[3];
    const int*   tail     = (const int*)d_in[4];
    const int*   g2l      = (const int*)d_in[5];
    const int*   res      = (const int*)d_in[6];
    const int*   nbs      = (const int*)d_in[7];
    const float* wts      = (const float*)d_in[8];
    const float* W1       = (const float*)d_in[9];
    const float* a1s      = (const float*)d_in[10];
    const float* a1d      = (const float*)d_in[11];
    const float* b1       = (const float*)d_in[12];
    const float* W2       = (const float*)d_in[13];
    const float* a2s      = (const float*)d_in[14];
    const float* a2d      = (const float*)d_in[15];
    const float* b2       = (const float*)d_in[16];
    const float* rel_emb  = (const float*)d_in[17];
    float* out = (float*)d_out;

    char* ws = (char*)d_ws;
    size_t off_b = 0;
    auto alloc = [&](size_t bytes) {
        void* pp = ws + off_b;
        off_b += (bytes + 255) & ~(size_t)255;
        return pp;
    };
    float*  bufB    = (float*)alloc((size_t)N_NODES * DIM * 4);  // layer out (fp32)
    ushort* hb      = (ushort*)alloc((size_t)N_NODES * DIM * 2); // bf16 h rows
    float*  hs      = (float*)alloc((size_t)N_NODES * 4);
    float*  hd      = (float*)alloc((size_t)N_NODES * 4);
    int*    deg     = (int*)alloc((size_t)N_NODES * 4);
    int*    offs    = (int*)alloc((size_t)(N_NODES + 1) * 4);
    int*    cnt     = (int*)alloc((size_t)N_NODES * 4);
    int*    csr_src = (int*)alloc((size_t)N_EDGES * 4);
    float*  cvals   = (float*)alloc((size_t)BSZ * 4);
    float*  vecpre  = (float*)alloc((size_t)BSZ * DIM * 4);
    int*    Wrows   = (int*)alloc((size_t)BSZ * 4);
    int*    flags   = (int*)alloc((size_t)BSZ * 4);
    ushort* apack   = (ushort*)alloc((size_t)M_PAD * 256 * 2);   // packed A (reused)
    ushort* wpack1  = (ushort*)alloc((size_t)256 * 256 * 2);
    ushort* wpack2  = (ushort*)alloc((size_t)256 * 256 * 2);

    const int edgeBlocks = (N_EDGES + 255) / 256;
    const int gemmBlocks = MTILES_PAD / 4;   // 782
    const int nodeBlocks4 = (N_NODES + 3) / 4;

    // ---------------- CSR build + weight packs (layer-invariant) ----
    hipMemsetAsync(deg, 0, (size_t)N_NODES * 4, stream);
    hipMemsetAsync(cnt, 0, (size_t)N_NODES * 4, stream);
    hist_kernel<<<edgeBlocks, 256, 0, stream>>>(ei, deg);
    scan_offsets_kernel<<<1, 256, 0, stream>>>(deg, offs);
    scatter_kernel<<<edgeBlocks, 256, 0, stream>>>(ei, offs, cnt, csr_src);
    pack_b_kernel<<<16, 256, 0, stream>>>(W1, wpack1);
    pack_b_kernel<<<16, 256, 0, stream>>>(W2, wpack2);

    // ---------------- layer 1 ----------------
    pack_a_kernel<<<MTILES_PAD, 256, 0, stream>>>(x, apack, N_NODES);
    gemm_bf16_kernel<<<gemmBlocks, 256, 0, stream>>>(apack, wpack1, hb, N_NODES);
    node_dots_kernel<<<nodeBlocks4, 256, 0, stream>>>(hb, a1s, a1d, hs, hd);
    gat_aggr_kernel<<<nodeBlocks4, 256, 0, stream>>>(offs, csr_src, hs, hd, hb, b1, bufB, 1);

    // ---------------- layer 2 ----------------
    pack_a_kernel<<<MTILES_PAD, 256, 0, stream>>>(bufB, apack, N_NODES);
    gemm_bf16_kernel<<<gemmBlocks, 256, 0, stream>>>(apack, wpack2, hb, N_NODES);
    node_dots_kernel<<<nodeBlocks4, 256, 0, stream>>>(hb, a2s, a2d, hs, hd);
    gat_aggr_kernel<<<nodeBlocks4, 256, 0, stream>>>(offs, csr_src, hs, hd, hb, b2, bufB, 0);

    // ---------------- scan (parallelized) + decode ----------------
    deg_c_kernel<<<BSZ, 256, 0, stream>>>(rel, head, g2l, res, cvals);
    prep_steps_kernel<<<BSZ, 256, 0, stream>>>(bufB, head, rel, g2l, nbs, wts,
                                               vecpre, Wrows, flags);
    conflict_kernel<<<BSZ, 256, 0, stream>>>(Wrows, head, rel, g2l, nbs, flags);
    apply_par_kernel<<<BSZ, 256, 0, stream>>>(bufB, head, rel, cvals, vecpre, flags);
    apply_seq_kernel<<<1, 256, 0, stream>>>(bufB, head, rel, g2l, nbs, wts, cvals, flags);
    decode_kernel<<<BSZ, 256, 0, stream>>>(bufB, head, rel, tail, rel_emb, out);
}

// Round 6
// 469.841 us; speedup vs baseline: 4.2581x; 1.2130x over previous
//
#include <hip/hip_runtime.h>
#include <cstdint>

#define N_NODES 50000
#define N_EDGES 800000
#define DIM     256
#define BSZ     256
#define ND_     5000
#define KNB     16
#define ER_     20000
#define LAM     0.7f

typedef unsigned int uint;
typedef unsigned short ushort;
typedef __attribute__((ext_vector_type(8))) short bf16x8;
typedef __attribute__((ext_vector_type(4))) float f32x4;

#define MTILES_PAD 3128            // ceil(50000/16) padded to multiple of 4
#define M_PAD      (MTILES_PAD*16) // 50048
#define NB_SCAN    ((N_NODES + 255) / 256)   // 196

__device__ __forceinline__ ushort f2bf(float f) {
    uint u = __float_as_uint(f);
    uint r = u + 0x7FFFu + ((u >> 16) & 1u);   // round-to-nearest-even
    return (ushort)(r >> 16);
}
__device__ __forceinline__ float bf2f(ushort u) {
    return __uint_as_float(((uint)u) << 16);
}

// fragment k-map: elem j, lane-group lg -> kk in [0,32)
// same bijection for A-pack and B-pack (permutation cancels): kk=(j&3)+lg*4+(j>>2)*16

// ------------------------------------- pack A [M,256] f32 -> frag-order bf16
__global__ __launch_bounds__(256)
void pack_a_kernel(const float* __restrict__ A, ushort* __restrict__ out, int M) {
    const int mt = blockIdx.x;
    const int t  = threadIdx.x;
    const int l  = t & 63;
    const int kt0 = (t >> 6) * 2;
    const int row = mt * 16 + (l & 15);
    const int lg  = l >> 4;
#pragma unroll
    for (int p = 0; p < 2; ++p) {
        int kt = kt0 + p;
        float4 v0 = make_float4(0.f, 0.f, 0.f, 0.f);
        float4 v1 = make_float4(0.f, 0.f, 0.f, 0.f);
        if (row < M) {
            v0 = *(const float4*)(A + (size_t)row * 256 + kt * 32 + lg * 4);
            v1 = *(const float4*)(A + (size_t)row * 256 + kt * 32 + lg * 4 + 16);
        }
        ushort us[8];
        us[0] = f2bf(v0.x); us[1] = f2bf(v0.y); us[2] = f2bf(v0.z); us[3] = f2bf(v0.w);
        us[4] = f2bf(v1.x); us[5] = f2bf(v1.y); us[6] = f2bf(v1.z); us[7] = f2bf(v1.w);
        ushort* dst = out + ((size_t)(mt * 8 + kt) * 64 + l) * 8;
        *(uint4*)dst = *(uint4*)us;
    }
}

// ------------------------------------- pack W [K=256,N=256] f32 -> frag order
__global__ __launch_bounds__(256)
void pack_b_kernel(const float* __restrict__ W, ushort* __restrict__ out) {
    const int nt = blockIdx.x;      // 16
    const int t  = threadIdx.x;
    const int l  = t & 63;
    const int kt0 = (t >> 6) * 2;
    const int n  = nt * 16 + (l & 15);
    const int lg = l >> 4;
#pragma unroll
    for (int p = 0; p < 2; ++p) {
        int kt = kt0 + p;
        ushort us[8];
#pragma unroll
        for (int j = 0; j < 8; ++j) {
            int kk = (j & 3) + lg * 4 + (j >> 2) * 16;
            us[j] = f2bf(W[(size_t)(kt * 32 + kk) * 256 + n]);
        }
        ushort* dst = out + ((size_t)(nt * 8 + kt) * 64 + l) * 8;
        *(uint4*)dst = *(uint4*)us;
    }
}

// ----------------------------------------------------------- bf16 MFMA GEMM
// H[M,256] (bf16 row-major) = A @ B ; block = 4 waves, 64 rows
__global__ __launch_bounds__(256)
void gemm_bf16_kernel(const ushort* __restrict__ Ap, const ushort* __restrict__ Bp,
                      ushort* __restrict__ H, int M) {
    const int w = threadIdx.x >> 6;
    const int l = threadIdx.x & 63;
    const int mt0 = blockIdx.x * 4;
    f32x4 acc[4][4];
#pragma unroll
    for (int i = 0; i < 4; ++i)
#pragma unroll
        for (int j = 0; j < 4; ++j) acc[i][j] = (f32x4){0.f, 0.f, 0.f, 0.f};

    for (int kt = 0; kt < 8; ++kt) {
        bf16x8 af[4], bfr[4];
#pragma unroll
        for (int mi = 0; mi < 4; ++mi)
            af[mi] = *(const bf16x8*)(Ap + ((size_t)((mt0 + mi) * 8 + kt) * 64 + l) * 8);
#pragma unroll
        for (int ni = 0; ni < 4; ++ni)
            bfr[ni] = *(const bf16x8*)(Bp + ((size_t)((w * 4 + ni) * 8 + kt) * 64 + l) * 8);
#pragma unroll
        for (int mi = 0; mi < 4; ++mi)
#pragma unroll
            for (int ni = 0; ni < 4; ++ni)
                acc[mi][ni] = __builtin_amdgcn_mfma_f32_16x16x32_bf16(
                    af[mi], bfr[ni], acc[mi][ni], 0, 0, 0);
    }
    const int rbase = (l >> 4) * 4;   // C/D: col=lane&15, row=(lane>>4)*4+reg  [m89/m91]
    const int cb    = (l & 15);
#pragma unroll
    for (int mi = 0; mi < 4; ++mi) {
        int row0 = (mt0 + mi) * 16 + rbase;
#pragma unroll
        for (int r = 0; r < 4; ++r) {
            int row = row0 + r;
            if (row < M) {
#pragma unroll
                for (int ni = 0; ni < 4; ++ni) {
                    int col = (w * 4 + ni) * 16 + cb;
                    H[(size_t)row * 256 + col] = f2bf(acc[mi][ni][r]);
                }
            }
        }
    }
}

// ------------------------- per-node attention dots (bf16 rows in)
__global__ __launch_bounds__(256)
void node_dots_kernel(const ushort* __restrict__ hb,
                      const float* __restrict__ a_src,
                      const float* __restrict__ a_dst,
                      float* __restrict__ hs, float* __restrict__ hd) {
    int node = blockIdx.x * 4 + (threadIdx.x >> 6);
    int lane = threadIdx.x & 63;
    if (node >= N_NODES) return;
    uint2 rv = *(const uint2*)(hb + (size_t)node * DIM + lane * 4);
    float f0 = __uint_as_float(rv.x << 16);
    float f1 = __uint_as_float(rv.x & 0xffff0000u);
    float f2 = __uint_as_float(rv.y << 16);
    float f3 = __uint_as_float(rv.y & 0xffff0000u);
    float4 as = ((const float4*)a_src)[lane];
    float4 ad = ((const float4*)a_dst)[lane];
    float ssum = f0 * as.x + f1 * as.y + f2 * as.z + f3 * as.w;
    float dsum = f0 * ad.x + f1 * ad.y + f2 * ad.z + f3 * ad.w;
#pragma unroll
    for (int off = 32; off; off >>= 1) {
        ssum += __shfl_down(ssum, off);
        dsum += __shfl_down(dsum, off);
    }
    if (lane == 0) { hs[node] = ssum; hd[node] = dsum; }
}

// -------------------------------------------------------------- CSR build
__global__ __launch_bounds__(256)
void hist_kernel(const int* __restrict__ ei, int* __restrict__ deg) {
    int e = blockIdx.x * 256 + threadIdx.x;
    if (e < N_EDGES) atomicAdd(&deg[ei[N_EDGES + e]], 1);
}

// -------- two-level parallel exclusive scan of deg -> offs (replaces the
// 100 µs single-block latency-bound scan) --------
__global__ __launch_bounds__(256)
void blockscan_kernel(const int* __restrict__ deg, int* __restrict__ off,
                      int* __restrict__ bsum) {
    __shared__ int s[256];
    const int b = blockIdx.x, t = threadIdx.x;
    const int idx = b * 256 + t;
    int v = (idx < N_NODES) ? deg[idx] : 0;
    s[t] = v;
    __syncthreads();
    for (int o = 1; o < 256; o <<= 1) {
        int x = (t >= o) ? s[t - o] : 0;
        __syncthreads();
        s[t] += x;
        __syncthreads();
    }
    if (idx < N_NODES) off[idx] = s[t] - v;    // exclusive within block
    if (t == 255) bsum[b] = s[255];
}

__global__ __launch_bounds__(256)
void scan_bsum_kernel(const int* __restrict__ bsum, int* __restrict__ bpre) {
    __shared__ int s[256];
    const int t = threadIdx.x;
    int v = (t < NB_SCAN) ? bsum[t] : 0;
    s[t] = v;
    __syncthreads();
    for (int o = 1; o < 256; o <<= 1) {
        int x = (t >= o) ? s[t - o] : 0;
        __syncthreads();
        s[t] += x;
        __syncthreads();
    }
    if (t < NB_SCAN) bpre[t] = s[t] - v;       // exclusive block prefix
    if (t == 255) bpre[NB_SCAN] = s[255];      // grand total
}

__global__ __launch_bounds__(256)
void add_offsets_kernel(int* __restrict__ off, const int* __restrict__ bpre) {
    const int b = blockIdx.x, t = threadIdx.x;
    const int idx = b * 256 + t;
    if (idx < N_NODES) off[idx] += bpre[b];
    if (b == NB_SCAN - 1 && t == 255) off[N_NODES] = bpre[NB_SCAN];
}

__global__ __launch_bounds__(256)
void scatter_kernel(const int* __restrict__ ei, const int* __restrict__ off,
                    int* __restrict__ cnt, int* __restrict__ csr_src) {
    int e = blockIdx.x * 256 + threadIdx.x;
    if (e >= N_EDGES) return;
    int d = ei[N_EDGES + e];
    int pos = atomicAdd(&cnt[d], 1);
    csr_src[off[d] + pos] = ei[e];
}

// ----------------- fused GAT edge stage: wave-per-dst, no max, no barriers
// softmax shift-invariance: alpha = exp(e)/sum(exp(e)); |e| <= ~10 so safe.
__global__ __launch_bounds__(256)
void gat_aggr_kernel(const int* __restrict__ off, const int* __restrict__ csr_src,
                     const float* __restrict__ hs, const float* __restrict__ hd,
                     const ushort* __restrict__ hb, const float* __restrict__ bias,
                     float* __restrict__ outbuf, int do_silu) {
    const int d = blockIdx.x * 4 + (threadIdx.x >> 6);
    const int l = threadIdx.x & 63;
    if (d >= N_NODES) return;
    const int beg = off[d], end = off[d + 1];
    const float hdd = hd[d];

    float acc0 = 0.f, acc1 = 0.f, acc2 = 0.f, acc3 = 0.f;
    float zl = 0.f;

    for (int c0 = beg; c0 < end; c0 += 64) {
        const int cn = min(end - c0, 64);
        int s = 0; float pexp = 0.f;
        if (l < cn) {
            s = csr_src[c0 + l];
            float v = hs[s] + hdd;
            v = (v >= 0.f) ? v : 0.2f * v;
            pexp = __expf(v);
        }
        zl += pexp;
        for (int j = 0; j < cn; ++j) {
            int   sj = __shfl(s, j);       // uniform j -> readlane
            float pj = __shfl(pexp, j);
            uint2 rv = *(const uint2*)(hb + (size_t)sj * DIM + l * 4);
            acc0 = fmaf(pj, __uint_as_float(rv.x << 16),          acc0);
            acc1 = fmaf(pj, __uint_as_float(rv.x & 0xffff0000u),  acc1);
            acc2 = fmaf(pj, __uint_as_float(rv.y << 16),          acc2);
            acc3 = fmaf(pj, __uint_as_float(rv.y & 0xffff0000u),  acc3);
        }
    }
    float z = zl;
#pragma unroll
    for (int o = 32; o; o >>= 1) z += __shfl_xor(z, o);
    const float inv = (end > beg) ? 1.f / (z + 1e-16f) : 0.f;
    float4 bb = *(const float4*)(bias + l * 4);
    float o0 = acc0 * inv + bb.x;
    float o1 = acc1 * inv + bb.y;
    float o2 = acc2 * inv + bb.z;
    float o3 = acc3 * inv + bb.w;
    if (do_silu) {
        o0 = o0 / (1.f + __expf(-o0));
        o1 = o1 / (1.f + __expf(-o1));
        o2 = o2 / (1.f + __expf(-o2));
        o3 = o3 / (1.f + __expf(-o3));
    }
    *(float4*)(outbuf + (size_t)d * DIM + l * 4) = make_float4(o0, o1, o2, o3);
}

// --------------------------------------------- precompute c[b] (deg counting)
__global__ __launch_bounds__(256)
void deg_c_kernel(const int* __restrict__ rel, const int* __restrict__ head,
                  const int* __restrict__ g2l, const int* __restrict__ res,
                  float* __restrict__ cvals) {
    int b = blockIdx.x;
    int r = rel[b];
    if (r < 4 || r > 6) { if (threadIdx.x == 0) cvals[b] = 0.f; return; }
    int local = g2l[head[b]];
    const int* rr = res + (size_t)(r - 4) * ER_;
    int cnt = 0;
    for (int i = threadIdx.x; i < ER_; i += 256) cnt += (rr[i] == local);
    __shared__ int sdeg;
    if (threadIdx.x == 0) sdeg = 0;
    __syncthreads();
#pragma unroll
    for (int off = 32; off; off >>= 1) cnt += __shfl_down(cnt, off);
    if ((threadIdx.x & 63) == 0) atomicAdd(&sdeg, cnt);
    __syncthreads();
    if (threadIdx.x == 0)
        cvals[b] = LAM * expf(-LAM * (float)sdeg) + 0.2f;
}

// -------------------------- parallelized sequential scan -------------------
__global__ __launch_bounds__(256)
void prep_steps_kernel(const float* __restrict__ emb, const int* __restrict__ head,
                       const int* __restrict__ rel, const int* __restrict__ g2l,
                       const int* __restrict__ nbs, const float* __restrict__ wts,
                       float* __restrict__ vecpre, int* __restrict__ W,
                       int* __restrict__ flags) {
    int b = blockIdx.x;
    int t = threadIdx.x;
    int r = rel[b];
    int dis = (r >= 4 && r <= 6);
    if (t == 0) { flags[b] = 0; W[b] = dis ? head[b] : -1; }
    if (!dis) return;
    int local = g2l[head[b]];
    const int* __restrict__ nb = nbs + (size_t)local * KNB;
    const float* __restrict__ w = wts + (size_t)local * KNB;
    float v0 = 0.f, v1 = 0.f;
#pragma unroll
    for (int k = 0; k < KNB; k += 2) {
        v0 = fmaf(w[k],     emb[(size_t)nb[k] * DIM + t],     v0);
        v1 = fmaf(w[k + 1], emb[(size_t)nb[k + 1] * DIM + t], v1);
    }
    vecpre[(size_t)b * DIM + t] = v0 + v1;
}

__global__ __launch_bounds__(256)
void conflict_kernel(const int* __restrict__ W, const int* __restrict__ head,
                     const int* __restrict__ rel, const int* __restrict__ g2l,
                     const int* __restrict__ nbs, int* __restrict__ flags) {
    int b = blockIdx.x;
    int r = rel[b];
    if (r < 4 || r > 6) return;
    __shared__ int rd[KNB + 1];
    int t = threadIdx.x;
    if (t == 0) rd[KNB] = head[b];
    if (t < KNB) {
        int local = g2l[head[b]];
        rd[t] = nbs[(size_t)local * KNB + t];
    }
    __syncthreads();
    int w = (t != b) ? W[t] : -1;
    if (w >= 0) {
        bool hit = false;
#pragma unroll
        for (int k = 0; k <= KNB; ++k) hit |= (rd[k] == w);
        if (hit) { flags[b] = 1; flags[t] = 1; }
    }
}

__global__ __launch_bounds__(256)
void apply_par_kernel(float* __restrict__ emb, const int* __restrict__ head,
                      const int* __restrict__ rel, const float* __restrict__ cvals,
                      const float* __restrict__ vecpre, const int* __restrict__ flags) {
    int b = blockIdx.x;
    int r = rel[b];
    if (r < 4 || r > 6) return;
    if (flags[b]) return;
    int t = threadIdx.x;
    int hi = head[b];
    float c = cvals[b];
    size_t idx = (size_t)hi * DIM + t;
    emb[idx] = c * vecpre[(size_t)b * DIM + t] + (1.f - c) * emb[idx];
}

__global__ __launch_bounds__(256)
void apply_seq_kernel(float* __restrict__ emb, const int* __restrict__ head,
                      const int* __restrict__ rel, const int* __restrict__ g2l,
                      const int* __restrict__ nbs, const float* __restrict__ wts,
                      const float* __restrict__ cvals, const int* __restrict__ flags) {
    __shared__ int   snb[BSZ][KNB];
    __shared__ float sw[BSZ][KNB];
    __shared__ int   sh[BSZ];
    __shared__ float sc[BSZ];
    __shared__ int   sf[BSZ];
    const int t = threadIdx.x;
    int r = rel[t];
    int dis = (r >= 4 && r <= 6);
    int hi = head[t];
    sh[t] = hi;
    sc[t] = cvals[t];
    sf[t] = dis ? flags[t] : 0;
    if (dis) {
        int local = g2l[hi];
#pragma unroll
        for (int k = 0; k < KNB; ++k) {
            snb[t][k] = nbs[(size_t)local * KNB + k];
            sw[t][k]  = wts[(size_t)local * KNB + k];
        }
    }
    __syncthreads();
    for (int b = 0; b < BSZ; ++b) {
        if (sf[b]) {
            int hh = sh[b];
            float c = sc[b];
            float v0 = 0.f, v1 = 0.f;
#pragma unroll
            for (int k = 0; k < KNB; k += 2) {
                v0 = fmaf(sw[b][k],     emb[(size_t)snb[b][k] * DIM + t],     v0);
                v1 = fmaf(sw[b][k + 1], emb[(size_t)snb[b][k + 1] * DIM + t], v1);
            }
            size_t idx = (size_t)hh * DIM + t;
            emb[idx] = c * (v0 + v1) + (1.f - c) * emb[idx];
        }
    }
}

// ------------------------------------------------------------------ decode
__global__ __launch_bounds__(256)
void decode_kernel(const float* __restrict__ emb, const int* __restrict__ head,
                   const int* __restrict__ rel, const int* __restrict__ tail,
                   const float* __restrict__ rel_emb, float* __restrict__ out) {
    int b = blockIdx.x, t = threadIdx.x;
    float v = emb[(size_t)head[b] * DIM + t] *
              rel_emb[(size_t)rel[b] * DIM + t] *
              emb[(size_t)tail[b] * DIM + t];
    __shared__ float red[4];
#pragma unroll
    for (int off = 32; off; off >>= 1) v += __shfl_down(v, off);
    int lane = t & 63, w = t >> 6;
    if (lane == 0) red[w] = v;
    __syncthreads();
    if (t == 0) {
        float s = red[0] + red[1] + red[2] + red[3];
        out[b] = 1.f / (1.f + expf(-s));
    }
}

// ------------------------------------------------------------------ launch
extern "C" void kernel_launch(void* const* d_in, const int* in_sizes, int n_in,
                              void* d_out, int out_size, void* d_ws, size_t ws_size,
                              hipStream_t stream) {
    const float* x        = (const float*)d_in[0];
    const int*   ei       = (const int*)d_in[1];
    const int*   head     = (const int*)d_in[2];
    const int*   rel      = (const int*)d_in[3];
    const int*   tail     = (const int*)d_in[4];
    const int*   g2l      = (const int*)d_in[5];
    const int*   res      = (const int*)d_in[6];
    const int*   nbs      = (const int*)d_in[7];
    const float* wts      = (const float*)d_in[8];
    const float* W1       = (const float*)d_in[9];
    const float* a1s      = (const float*)d_in[10];
    const float* a1d      = (const float*)d_in[11];
    const float* b1       = (const float*)d_in[12];
    const float* W2       = (const float*)d_in[13];
    const float* a2s      = (const float*)d_in[14];
    const float* a2d      = (const float*)d_in[15];
    const float* b2       = (const float*)d_in[16];
    const float* rel_emb  = (const float*)d_in[17];
    float* out = (float*)d_out;

    char* ws = (char*)d_ws;
    size_t off_b = 0;
    auto alloc = [&](size_t bytes) {
        void* pp = ws + off_b;
        off_b += (bytes + 255) & ~(size_t)255;
        return pp;
    };
    float*  bufB    = (float*)alloc((size_t)N_NODES * DIM * 4);  // layer out (fp32)
    ushort* hb      = (ushort*)alloc((size_t)N_NODES * DIM * 2); // bf16 h rows
    float*  hs      = (float*)alloc((size_t)N_NODES * 4);
    float*  hd      = (float*)alloc((size_t)N_NODES * 4);
    int*    deg     = (int*)alloc((size_t)N_NODES * 4);
    int*    offs    = (int*)alloc((size_t)(N_NODES + 1) * 4);
    int*    cnt     = (int*)alloc((size_t)N_NODES * 4);
    int*    csr_src = (int*)alloc((size_t)N_EDGES * 4);
    int*    bsum    = (int*)alloc((size_t)NB_SCAN * 4);
    int*    bpre    = (int*)alloc((size_t)(NB_SCAN + 1) * 4);
    float*  cvals   = (float*)alloc((size_t)BSZ * 4);
    float*  vecpre  = (float*)alloc((size_t)BSZ * DIM * 4);
    int*    Wrows   = (int*)alloc((size_t)BSZ * 4);
    int*    flags   = (int*)alloc((size_t)BSZ * 4);
    ushort* apack   = (ushort*)alloc((size_t)M_PAD * 256 * 2);   // packed A (reused)
    ushort* wpack1  = (ushort*)alloc((size_t)256 * 256 * 2);
    ushort* wpack2  = (ushort*)alloc((size_t)256 * 256 * 2);

    const int edgeBlocks = (N_EDGES + 255) / 256;
    const int gemmBlocks = MTILES_PAD / 4;   // 782
    const int nodeBlocks4 = (N_NODES + 3) / 4;

    // ---------------- CSR build + weight packs (layer-invariant) ----
    hipMemsetAsync(deg, 0, (size_t)N_NODES * 4, stream);
    hipMemsetAsync(cnt, 0, (size_t)N_NODES * 4, stream);
    hist_kernel<<<edgeBlocks, 256, 0, stream>>>(ei, deg);
    blockscan_kernel<<<NB_SCAN, 256, 0, stream>>>(deg, offs, bsum);
    scan_bsum_kernel<<<1, 256, 0, stream>>>(bsum, bpre);
    add_offsets_kernel<<<NB_SCAN, 256, 0, stream>>>(offs, bpre);
    scatter_kernel<<<edgeBlocks, 256, 0, stream>>>(ei, offs, cnt, csr_src);
    pack_b_kernel<<<16, 256, 0, stream>>>(W1, wpack1);
    pack_b_kernel<<<16, 256, 0, stream>>>(W2, wpack2);

    // ---------------- layer 1 ----------------
    pack_a_kernel<<<MTILES_PAD, 256, 0, stream>>>(x, apack, N_NODES);
    gemm_bf16_kernel<<<gemmBlocks, 256, 0, stream>>>(apack, wpack1, hb, N_NODES);
    node_dots_kernel<<<nodeBlocks4, 256, 0, stream>>>(hb, a1s, a1d, hs, hd);
    gat_aggr_kernel<<<nodeBlocks4, 256, 0, stream>>>(offs, csr_src, hs, hd, hb, b1, bufB, 1);

    // ---------------- layer 2 ----------------
    pack_a_kernel<<<MTILES_PAD, 256, 0, stream>>>(bufB, apack, N_NODES);
    gemm_bf16_kernel<<<gemmBlocks, 256, 0, stream>>>(apack, wpack2, hb, N_NODES);
    node_dots_kernel<<<nodeBlocks4, 256, 0, stream>>>(hb, a2s, a2d, hs, hd);
    gat_aggr_kernel<<<nodeBlocks4, 256, 0, stream>>>(offs, csr_src, hs, hd, hb, b2, bufB, 0);

    // ---------------- scan (parallelized) + decode ----------------
    deg_c_kernel<<<BSZ, 256, 0, stream>>>(rel, head, g2l, res, cvals);
    prep_steps_kernel<<<BSZ, 256, 0, stream>>>(bufB, head, rel, g2l, nbs, wts,
                                               vecpre, Wrows, flags);
    conflict_kernel<<<BSZ, 256, 0, stream>>>(Wrows, head, rel, g2l, nbs, flags);
    apply_par_kernel<<<BSZ, 256, 0, stream>>>(bufB, head, rel, cvals, vecpre, flags);
    apply_seq_kernel<<<1, 256, 0, stream>>>(bufB, head, rel, g2l, nbs, wts, cvals, flags);
    decode_kernel<<<BSZ, 256, 0, stream>>>(bufB, head, rel, tail, rel_emb, out);
}

// Round 8
// 427.505 us; speedup vs baseline: 4.6798x; 1.0990x over previous
//
#include <hip/hip_runtime.h>
#include <cstdint>

#define N_NODES 50000
#define N_EDGES 800000
#define DIM     256
#define BSZ     256
#define ND_     5000
#define KNB     16
#define ER_     20000
#define LAM     0.7f

typedef unsigned int uint;
typedef unsigned short ushort;
typedef __attribute__((ext_vector_type(8))) short bf16x8;
typedef __attribute__((ext_vector_type(4))) float f32x4;

#define MTILES_PAD 3128            // ceil(50000/16) padded to multiple of 4
#define M_PAD      (MTILES_PAD*16) // 50048
#define NB_SCAN    ((N_NODES + 255) / 256)   // 196

__device__ __forceinline__ ushort f2bf(float f) {
    uint u = __float_as_uint(f);
    uint r = u + 0x7FFFu + ((u >> 16) & 1u);   // round-to-nearest-even
    return (ushort)(r >> 16);
}
__device__ __forceinline__ float bflo(uint u) { return __uint_as_float(u << 16); }
__device__ __forceinline__ float bfhi(uint u) { return __uint_as_float(u & 0xffff0000u); }

// fragment k-map: elem j, lane-group lg -> kk in [0,32)
// same bijection for A-pack and B-pack (permutation cancels): kk=(j&3)+lg*4+(j>>2)*16

// ------------------------------------- pack A [M,256] f32 -> frag-order bf16
__global__ __launch_bounds__(256)
void pack_a_kernel(const float* __restrict__ A, ushort* __restrict__ out, int M) {
    const int mt = blockIdx.x;
    const int t  = threadIdx.x;
    const int l  = t & 63;
    const int kt0 = (t >> 6) * 2;
    const int row = mt * 16 + (l & 15);
    const int lg  = l >> 4;
#pragma unroll
    for (int p = 0; p < 2; ++p) {
        int kt = kt0 + p;
        float4 v0 = make_float4(0.f, 0.f, 0.f, 0.f);
        float4 v1 = make_float4(0.f, 0.f, 0.f, 0.f);
        if (row < M) {
            v0 = *(const float4*)(A + (size_t)row * 256 + kt * 32 + lg * 4);
            v1 = *(const float4*)(A + (size_t)row * 256 + kt * 32 + lg * 4 + 16);
        }
        ushort us[8];
        us[0] = f2bf(v0.x); us[1] = f2bf(v0.y); us[2] = f2bf(v0.z); us[3] = f2bf(v0.w);
        us[4] = f2bf(v1.x); us[5] = f2bf(v1.y); us[6] = f2bf(v1.z); us[7] = f2bf(v1.w);
        ushort* dst = out + ((size_t)(mt * 8 + kt) * 64 + l) * 8;
        *(uint4*)dst = *(uint4*)us;
    }
}

// --------------------------- pack A from bf16 row-major (pure data movement)
__global__ __launch_bounds__(256)
void pack_a_bf16_kernel(const ushort* __restrict__ A, ushort* __restrict__ out, int M) {
    const int mt = blockIdx.x;
    const int t  = threadIdx.x;
    const int l  = t & 63;
    const int kt0 = (t >> 6) * 2;
    const int row = mt * 16 + (l & 15);
    const int lg  = l >> 4;
#pragma unroll
    for (int p = 0; p < 2; ++p) {
        int kt = kt0 + p;
        uint2 v0 = make_uint2(0u, 0u), v1 = make_uint2(0u, 0u);
        if (row < M) {
            v0 = *(const uint2*)(A + (size_t)row * 256 + kt * 32 + lg * 4);        // kk j=0..3
            v1 = *(const uint2*)(A + (size_t)row * 256 + kt * 32 + 16 + lg * 4);   // kk j=4..7
        }
        uint4 o; o.x = v0.x; o.y = v0.y; o.z = v1.x; o.w = v1.y;
        *(uint4*)(out + ((size_t)(mt * 8 + kt) * 64 + l) * 8) = o;
    }
}

// ------------------------------------- pack W [K=256,N=256] f32 -> frag order
__global__ __launch_bounds__(256)
void pack_b_kernel(const float* __restrict__ W, ushort* __restrict__ out) {
    const int nt = blockIdx.x;      // 16
    const int t  = threadIdx.x;
    const int l  = t & 63;
    const int kt0 = (t >> 6) * 2;
    const int n  = nt * 16 + (l & 15);
    const int lg = l >> 4;
#pragma unroll
    for (int p = 0; p < 2; ++p) {
        int kt = kt0 + p;
        ushort us[8];
#pragma unroll
        for (int j = 0; j < 8; ++j) {
            int kk = (j & 3) + lg * 4 + (j >> 2) * 16;
            us[j] = f2bf(W[(size_t)(kt * 32 + kk) * 256 + n]);
        }
        ushort* dst = out + ((size_t)(nt * 8 + kt) * 64 + l) * 8;
        *(uint4*)dst = *(uint4*)us;
    }
}

// ------------------------- bf16 MFMA GEMM + fused attention dots epilogue
// H[M,256] (bf16 row-major) = A @ B ; hs/hd = H @ a_src / H @ a_dst
__global__ __launch_bounds__(256)
void gemm_bf16_kernel(const ushort* __restrict__ Ap, const ushort* __restrict__ Bp,
                      ushort* __restrict__ H,
                      const float* __restrict__ a_src, const float* __restrict__ a_dst,
                      float* __restrict__ hs, float* __restrict__ hd, int M) {
    __shared__ float sdS[4][64];
    __shared__ float sdD[4][64];
    const int t = threadIdx.x;
    const int w = t >> 6;
    const int l = t & 63;
    const int mt0 = blockIdx.x * 4;
    f32x4 acc[4][4];
#pragma unroll
    for (int i = 0; i < 4; ++i)
#pragma unroll
        for (int j = 0; j < 4; ++j) acc[i][j] = (f32x4){0.f, 0.f, 0.f, 0.f};

    for (int kt = 0; kt < 8; ++kt) {
        bf16x8 af[4], bfr[4];
#pragma unroll
        for (int mi = 0; mi < 4; ++mi)
            af[mi] = *(const bf16x8*)(Ap + ((size_t)((mt0 + mi) * 8 + kt) * 64 + l) * 8);
#pragma unroll
        for (int ni = 0; ni < 4; ++ni)
            bfr[ni] = *(const bf16x8*)(Bp + ((size_t)((w * 4 + ni) * 8 + kt) * 64 + l) * 8);
#pragma unroll
        for (int mi = 0; mi < 4; ++mi)
#pragma unroll
            for (int ni = 0; ni < 4; ++ni)
                acc[mi][ni] = __builtin_amdgcn_mfma_f32_16x16x32_bf16(
                    af[mi], bfr[ni], acc[mi][ni], 0, 0, 0);
    }
    const int rbase = (l >> 4) * 4;   // C/D: col=lane&15, row=(lane>>4)*4+reg  [m89/m91]
    const int cb    = (l & 15);
    // per-lane a_src/a_dst for this lane's 4 columns
    float asv[4], adv[4];
#pragma unroll
    for (int ni = 0; ni < 4; ++ni) {
        int col = (w * 4 + ni) * 16 + cb;
        asv[ni] = a_src[col];
        adv[ni] = a_dst[col];
    }
#pragma unroll
    for (int mi = 0; mi < 4; ++mi) {
#pragma unroll
        for (int r = 0; r < 4; ++r) {
            int row = (mt0 + mi) * 16 + rbase + r;
            float ps = 0.f, pd = 0.f;
#pragma unroll
            for (int ni = 0; ni < 4; ++ni) {
                float hv = acc[mi][ni][r];
                ps = fmaf(hv, asv[ni], ps);
                pd = fmaf(hv, adv[ni], pd);
                if (row < M) {
                    int col = (w * 4 + ni) * 16 + cb;
                    H[(size_t)row * 256 + col] = f2bf(hv);
                }
            }
            // reduce over the 16 lanes sharing this row (xor within 16-group)
#pragma unroll
            for (int o = 1; o < 16; o <<= 1) {
                ps += __shfl_xor(ps, o);
                pd += __shfl_xor(pd, o);
            }
            if (cb == 0) {
                sdS[w][mi * 16 + rbase + r] = ps;
                sdD[w][mi * 16 + rbase + r] = pd;
            }
        }
    }
    __syncthreads();
    if (t < 64) {
        int row = mt0 * 16 + t;
        if (row < M) {
            hs[row] = sdS[0][t] + sdS[1][t] + sdS[2][t] + sdS[3][t];
            hd[row] = sdD[0][t] + sdD[1][t] + sdD[2][t] + sdD[3][t];
        }
    }
}

// -------------------------------------------------------------- CSR build
__global__ __launch_bounds__(256)
void hist_kernel(const int* __restrict__ ei, int* __restrict__ deg) {
    int e = blockIdx.x * 256 + threadIdx.x;
    if (e < N_EDGES) atomicAdd(&deg[ei[N_EDGES + e]], 1);
}

// -------- two-level parallel exclusive scan of deg -> offs --------
__global__ __launch_bounds__(256)
void blockscan_kernel(const int* __restrict__ deg, int* __restrict__ off,
                      int* __restrict__ bsum) {
    __shared__ int s[256];
    const int b = blockIdx.x, t = threadIdx.x;
    const int idx = b * 256 + t;
    int v = (idx < N_NODES) ? deg[idx] : 0;
    s[t] = v;
    __syncthreads();
    for (int o = 1; o < 256; o <<= 1) {
        int x = (t >= o) ? s[t - o] : 0;
        __syncthreads();
        s[t] += x;
        __syncthreads();
    }
    if (idx < N_NODES) off[idx] = s[t] - v;    // exclusive within block
    if (t == 255) bsum[b] = s[255];
}

__global__ __launch_bounds__(256)
void scan_bsum_kernel(const int* __restrict__ bsum, int* __restrict__ bpre) {
    __shared__ int s[256];
    const int t = threadIdx.x;
    int v = (t < NB_SCAN) ? bsum[t] : 0;
    s[t] = v;
    __syncthreads();
    for (int o = 1; o < 256; o <<= 1) {
        int x = (t >= o) ? s[t - o] : 0;
        __syncthreads();
        s[t] += x;
        __syncthreads();
    }
    if (t < NB_SCAN) bpre[t] = s[t] - v;       // exclusive block prefix
    if (t == 255) bpre[NB_SCAN] = s[255];      // grand total
}

__global__ __launch_bounds__(256)
void add_offsets_kernel(int* __restrict__ off, const int* __restrict__ bpre) {
    const int b = blockIdx.x, t = threadIdx.x;
    const int idx = b * 256 + t;
    if (idx < N_NODES) off[idx] += bpre[b];
    if (b == NB_SCAN - 1 && t == 255) off[N_NODES] = bpre[NB_SCAN];
}

__global__ __launch_bounds__(256)
void scatter_kernel(const int* __restrict__ ei, const int* __restrict__ off,
                    int* __restrict__ cnt, int* __restrict__ csr_src) {
    int e = blockIdx.x * 256 + threadIdx.x;
    if (e >= N_EDGES) return;
    int d = ei[N_EDGES + e];
    int pos = atomicAdd(&cnt[d], 1);
    csr_src[off[d] + pos] = ei[e];
}

// ----------------- fused GAT edge stage: wave-per-dst, no max, no barriers
// 4x-unrolled gather for memory-level parallelism (latency-bound kernel).
__global__ __launch_bounds__(256)
void gat_aggr_kernel(const int* __restrict__ off, const int* __restrict__ csr_src,
                     const float* __restrict__ hs, const float* __restrict__ hd,
                     const ushort* __restrict__ hb, const float* __restrict__ bias,
                     float* __restrict__ out_f32, ushort* __restrict__ out_bf,
                     int do_silu) {
    const int d = blockIdx.x * 4 + (threadIdx.x >> 6);
    const int l = threadIdx.x & 63;
    if (d >= N_NODES) return;
    const int beg = off[d], end = off[d + 1];
    const float hdd = hd[d];

    float acc0 = 0.f, acc1 = 0.f, acc2 = 0.f, acc3 = 0.f;
    float zl = 0.f;
    const ushort* __restrict__ hcol = hb + l * 4;

    for (int c0 = beg; c0 < end; c0 += 64) {
        const int cn = min(end - c0, 64);
        int s = 0; float pexp = 0.f;
        if (l < cn) {
            s = csr_src[c0 + l];
            float v = hs[s] + hdd;
            v = (v >= 0.f) ? v : 0.2f * v;
            pexp = __expf(v);
        }
        zl += pexp;
        int j = 0;
        for (; j + 4 <= cn; j += 4) {
            int   s0 = __shfl(s, j),     s1 = __shfl(s, j + 1);
            int   s2 = __shfl(s, j + 2), s3 = __shfl(s, j + 3);
            float p0 = __shfl(pexp, j),     p1 = __shfl(pexp, j + 1);
            float p2 = __shfl(pexp, j + 2), p3 = __shfl(pexp, j + 3);
            uint2 r0 = *(const uint2*)(hcol + (size_t)s0 * DIM);
            uint2 r1 = *(const uint2*)(hcol + (size_t)s1 * DIM);
            uint2 r2 = *(const uint2*)(hcol + (size_t)s2 * DIM);
            uint2 r3 = *(const uint2*)(hcol + (size_t)s3 * DIM);
            acc0 = fmaf(p0, bflo(r0.x), acc0); acc1 = fmaf(p0, bfhi(r0.x), acc1);
            acc2 = fmaf(p0, bflo(r0.y), acc2); acc3 = fmaf(p0, bfhi(r0.y), acc3);
            acc0 = fmaf(p1, bflo(r1.x), acc0); acc1 = fmaf(p1, bfhi(r1.x), acc1);
            acc2 = fmaf(p1, bflo(r1.y), acc2); acc3 = fmaf(p1, bfhi(r1.y), acc3);
            acc0 = fmaf(p2, bflo(r2.x), acc0); acc1 = fmaf(p2, bfhi(r2.x), acc1);
            acc2 = fmaf(p2, bflo(r2.y), acc2); acc3 = fmaf(p2, bfhi(r2.y), acc3);
            acc0 = fmaf(p3, bflo(r3.x), acc0); acc1 = fmaf(p3, bfhi(r3.x), acc1);
            acc2 = fmaf(p3, bflo(r3.y), acc2); acc3 = fmaf(p3, bfhi(r3.y), acc3);
        }
        for (; j < cn; ++j) {
            int   sj = __shfl(s, j);
            float pj = __shfl(pexp, j);
            uint2 rv = *(const uint2*)(hcol + (size_t)sj * DIM);
            acc0 = fmaf(pj, bflo(rv.x), acc0); acc1 = fmaf(pj, bfhi(rv.x), acc1);
            acc2 = fmaf(pj, bflo(rv.y), acc2); acc3 = fmaf(pj, bfhi(rv.y), acc3);
        }
    }
    float z = zl;
#pragma unroll
    for (int o = 32; o; o >>= 1) z += __shfl_xor(z, o);
    const float inv = (end > beg) ? 1.f / (z + 1e-16f) : 0.f;
    float4 bb = *(const float4*)(bias + l * 4);
    float o0 = acc0 * inv + bb.x;
    float o1 = acc1 * inv + bb.y;
    float o2 = acc2 * inv + bb.z;
    float o3 = acc3 * inv + bb.w;
    if (do_silu) {
        o0 = o0 / (1.f + __expf(-o0));
        o1 = o1 / (1.f + __expf(-o1));
        o2 = o2 / (1.f + __expf(-o2));
        o3 = o3 / (1.f + __expf(-o3));
    }
    if (out_bf) {
        ushort us[4] = {f2bf(o0), f2bf(o1), f2bf(o2), f2bf(o3)};
        *(uint2*)(out_bf + (size_t)d * DIM + l * 4) = *(uint2*)us;
    } else {
        *(float4*)(out_f32 + (size_t)d * DIM + l * 4) = make_float4(o0, o1, o2, o3);
    }
}

// ------------------------------- rel-degree histogram + c-values (scan prep)
__global__ __launch_bounds__(256)
void rel_hist_kernel(const int* __restrict__ res, int* __restrict__ rhist) {
    int i = blockIdx.x * 256 + threadIdx.x;
    if (i < 3 * ER_) atomicAdd(&rhist[(i / ER_) * ND_ + res[i]], 1);
}

__global__ __launch_bounds__(256)
void cvals_kernel(const int* __restrict__ rel, const int* __restrict__ head,
                  const int* __restrict__ g2l, const int* __restrict__ rhist,
                  float* __restrict__ cvals) {
    int b = threadIdx.x;
    int r = rel[b];
    float c = 0.f;
    if (r >= 4 && r <= 6) {
        int local = g2l[head[b]];
        int deg = rhist[(r - 4) * ND_ + local];
        c = LAM * __expf(-LAM * (float)deg) + 0.2f;
    }
    cvals[b] = c;
}

// -------------------------- parallelized sequential scan -------------------
__global__ __launch_bounds__(256)
void prep_steps_kernel(const float* __restrict__ emb, const int* __restrict__ head,
                       const int* __restrict__ rel, const int* __restrict__ g2l,
                       const int* __restrict__ nbs, const float* __restrict__ wts,
                       float* __restrict__ vecpre, int* __restrict__ W,
                       int* __restrict__ flags) {
    int b = blockIdx.x;
    int t = threadIdx.x;
    int r = rel[b];
    int dis = (r >= 4 && r <= 6);
    if (t == 0) { flags[b] = 0; W[b] = dis ? head[b] : -1; }
    if (!dis) return;
    int local = g2l[head[b]];
    const int* __restrict__ nb = nbs + (size_t)local * KNB;
    const float* __restrict__ w = wts + (size_t)local * KNB;
    float v0 = 0.f, v1 = 0.f;
#pragma unroll
    for (int k = 0; k < KNB; k += 2) {
        v0 = fmaf(w[k],     emb[(size_t)nb[k] * DIM + t],     v0);
        v1 = fmaf(w[k + 1], emb[(size_t)nb[k + 1] * DIM + t], v1);
    }
    vecpre[(size_t)b * DIM + t] = v0 + v1;
}

__global__ __launch_bounds__(256)
void conflict_kernel(const int* __restrict__ W, const int* __restrict__ head,
                     const int* __restrict__ rel, const int* __restrict__ g2l,
                     const int* __restrict__ nbs, int* __restrict__ flags) {
    int b = blockIdx.x;
    int r = rel[b];
    if (r < 4 || r > 6) return;
    __shared__ int rd[KNB + 1];
    int t = threadIdx.x;
    if (t == 0) rd[KNB] = head[b];
    if (t < KNB) {
        int local = g2l[head[b]];
        rd[t] = nbs[(size_t)local * KNB + t];
    }
    __syncthreads();
    int w = (t != b) ? W[t] : -1;
    if (w >= 0) {
        bool hit = false;
#pragma unroll
        for (int k = 0; k <= KNB; ++k) hit |= (rd[k] == w);
        if (hit) { flags[b] = 1; flags[t] = 1; }
    }
}

__global__ __launch_bounds__(256)
void apply_par_kernel(float* __restrict__ emb, const int* __restrict__ head,
                      const int* __restrict__ rel, const float* __restrict__ cvals,
                      const float* __restrict__ vecpre, const int* __restrict__ flags) {
    int b = blockIdx.x;
    int r = rel[b];
    if (r < 4 || r > 6) return;
    if (flags[b]) return;
    int t = threadIdx.x;
    int hi = head[b];
    float c = cvals[b];
    size_t idx = (size_t)hi * DIM + t;
    emb[idx] = c * vecpre[(size_t)b * DIM + t] + (1.f - c) * emb[idx];
}

__global__ __launch_bounds__(256)
void apply_seq_kernel(float* __restrict__ emb, const int* __restrict__ head,
                      const int* __restrict__ rel, const int* __restrict__ g2l,
                      const int* __restrict__ nbs, const float* __restrict__ wts,
                      const float* __restrict__ cvals, const int* __restrict__ flags) {
    __shared__ int   snb[BSZ][KNB];
    __shared__ float sw[BSZ][KNB];
    __shared__ int   sh[BSZ];
    __shared__ float sc[BSZ];
    __shared__ int   sf[BSZ];
    const int t = threadIdx.x;
    int r = rel[t];
    int dis = (r >= 4 && r <= 6);
    int hi = head[t];
    sh[t] = hi;
    sc[t] = cvals[t];
    sf[t] = dis ? flags[t] : 0;
    if (dis) {
        int local = g2l[hi];
#pragma unroll
        for (int k = 0; k < KNB; ++k) {
            snb[t][k] = nbs[(size_t)local * KNB + k];
            sw[t][k]  = wts[(size_t)local * KNB + k];
        }
    }
    __syncthreads();
    for (int b = 0; b < BSZ; ++b) {
        if (sf[b]) {
            int hh = sh[b];
            float c = sc[b];
            float v0 = 0.f, v1 = 0.f;
#pragma unroll
            for (int k = 0; k < KNB; k += 2) {
                v0 = fmaf(sw[b][k],     emb[(size_t)snb[b][k] * DIM + t],     v0);
                v1 = fmaf(sw[b][k + 1], emb[(size_t)snb[b][k + 1] * DIM + t], v1);
            }
            size_t idx = (size_t)hh * DIM + t;
            emb[idx] = c * (v0 + v1) + (1.f - c) * emb[idx];
        }
    }
}

// ------------------------------------------------------------------ decode
__global__ __launch_bounds__(256)
void decode_kernel(const float* __restrict__ emb, const int* __restrict__ head,
                   const int* __restrict__ rel, const int* __restrict__ tail,
                   const float* __restrict__ rel_emb, float* __restrict__ out) {
    int b = blockIdx.x, t = threadIdx.x;
    float v = emb[(size_t)head[b] * DIM + t] *
              rel_emb[(size_t)rel[b] * DIM + t] *
              emb[(size_t)tail[b] * DIM + t];
    __shared__ float red[4];
#pragma unroll
    for (int off = 32; off; off >>= 1) v += __shfl_down(v, off);
    int lane = t & 63, w = t >> 6;
    if (lane == 0) red[w] = v;
    __syncthreads();
    if (t == 0) {
        float s = red[0] + red[1] + red[2] + red[3];
        out[b] = 1.f / (1.f + expf(-s));
    }
}

// ------------------------------------------------------------------ launch
extern "C" void kernel_launch(void* const* d_in, const int* in_sizes, int n_in,
                              void* d_out, int out_size, void* d_ws, size_t ws_size,
                              hipStream_t stream) {
    const float* x        = (const float*)d_in[0];
    const int*   ei       = (const int*)d_in[1];
    const int*   head     = (const int*)d_in[2];
    const int*   rel      = (const int*)d_in[3];
    const int*   tail     = (const int*)d_in[4];
    const int*   g2l      = (const int*)d_in[5];
    const int*   res      = (const int*)d_in[6];
    const int*   nbs      = (const int*)d_in[7];
    const float* wts      = (const float*)d_in[8];
    const float* W1       = (const float*)d_in[9];
    const float* a1s      = (const float*)d_in[10];
    const float* a1d      = (const float*)d_in[11];
    const float* b1       = (const float*)d_in[12];
    const float* W2       = (const float*)d_in[13];
    const float* a2s      = (const float*)d_in[14];
    const float* a2d      = (const float*)d_in[15];
    const float* b2       = (const float*)d_in[16];
    const float* rel_emb  = (const float*)d_in[17];
    float* out = (float*)d_out;

    char* ws = (char*)d_ws;
    size_t off_b = 0;
    auto alloc = [&](size_t bytes) {
        void* pp = ws + off_b;
        off_b += (bytes + 255) & ~(size_t)255;
        return pp;
    };
    float*  bufB    = (float*)alloc((size_t)N_NODES * DIM * 4);  // layer-2 out (fp32)
    ushort* hb      = (ushort*)alloc((size_t)N_NODES * DIM * 2); // bf16 h rows (gemm out)
    ushort* h1b     = (ushort*)alloc((size_t)N_NODES * DIM * 2); // bf16 layer-1 out
    float*  hs      = (float*)alloc((size_t)N_NODES * 4);
    float*  hd      = (float*)alloc((size_t)N_NODES * 4);
    int*    deg     = (int*)alloc((size_t)N_NODES * 4);
    int*    offs    = (int*)alloc((size_t)(N_NODES + 1) * 4);
    int*    cnt     = (int*)alloc((size_t)N_NODES * 4);
    int*    csr_src = (int*)alloc((size_t)N_EDGES * 4);
    int*    bsum    = (int*)alloc((size_t)NB_SCAN * 4);
    int*    bpre    = (int*)alloc((size_t)(NB_SCAN + 1) * 4);
    int*    rhist   = (int*)alloc((size_t)3 * ND_ * 4);
    float*  cvals   = (float*)alloc((size_t)BSZ * 4);
    float*  vecpre  = (float*)alloc((size_t)BSZ * DIM * 4);
    int*    Wrows   = (int*)alloc((size_t)BSZ * 4);
    int*    flags   = (int*)alloc((size_t)BSZ * 4);
    ushort* apack   = (ushort*)alloc((size_t)M_PAD * 256 * 2);   // packed A (reused)
    ushort* wpack1  = (ushort*)alloc((size_t)256 * 256 * 2);
    ushort* wpack2  = (ushort*)alloc((size_t)256 * 256 * 2);

    const int edgeBlocks = (N_EDGES + 255) / 256;
    const int gemmBlocks = MTILES_PAD / 4;   // 782
    const int nodeBlocks4 = (N_NODES + 3) / 4;

    // ---------------- CSR build + weight packs + rel histogram ----
    hipMemsetAsync(deg, 0, (size_t)N_NODES * 4, stream);
    hipMemsetAsync(cnt, 0, (size_t)N_NODES * 4, stream);
    hipMemsetAsync(rhist, 0, (size_t)3 * ND_ * 4, stream);
    hist_kernel<<<edgeBlocks, 256, 0, stream>>>(ei, deg);
    blockscan_kernel<<<NB_SCAN, 256, 0, stream>>>(deg, offs, bsum);
    scan_bsum_kernel<<<1, 256, 0, stream>>>(bsum, bpre);
    add_offsets_kernel<<<NB_SCAN, 256, 0, stream>>>(offs, bpre);
    scatter_kernel<<<edgeBlocks, 256, 0, stream>>>(ei, offs, cnt, csr_src);
    pack_b_kernel<<<16, 256, 0, stream>>>(W1, wpack1);
    pack_b_kernel<<<16, 256, 0, stream>>>(W2, wpack2);
    rel_hist_kernel<<<(3 * ER_ + 255) / 256, 256, 0, stream>>>(res, rhist);

    // ---------------- layer 1 ----------------
    pack_a_kernel<<<MTILES_PAD, 256, 0, stream>>>(x, apack, N_NODES);
    gemm_bf16_kernel<<<gemmBlocks, 256, 0, stream>>>(apack, wpack1, hb, a1s, a1d,
                                                     hs, hd, N_NODES);
    gat_aggr_kernel<<<nodeBlocks4, 256, 0, stream>>>(offs, csr_src, hs, hd, hb, b1,
                                                     nullptr, h1b, 1);

    // ---------------- layer 2 ----------------
    pack_a_bf16_kernel<<<MTILES_PAD, 256, 0, stream>>>(h1b, apack, N_NODES);
    gemm_bf16_kernel<<<gemmBlocks, 256, 0, stream>>>(apack, wpack2, hb, a2s, a2d,
                                                     hs, hd, N_NODES);
    gat_aggr_kernel<<<nodeBlocks4, 256, 0, stream>>>(offs, csr_src, hs, hd, hb, b2,
                                                     bufB, nullptr, 0);

    // ---------------- scan (parallelized) + decode ----------------
    cvals_kernel<<<1, 256, 0, stream>>>(rel, head, g2l, rhist, cvals);
    prep_steps_kernel<<<BSZ, 256, 0, stream>>>(bufB, head, rel, g2l, nbs, wts,
                                               vecpre, Wrows, flags);
    conflict_kernel<<<BSZ, 256, 0, stream>>>(Wrows, head, rel, g2l, nbs, flags);
    apply_par_kernel<<<BSZ, 256, 0, stream>>>(bufB, head, rel, cvals, vecpre, flags);
    apply_seq_kernel<<<1, 256, 0, stream>>>(bufB, head, rel, g2l, nbs, wts, cvals, flags);
    decode_kernel<<<BSZ, 256, 0, stream>>>(bufB, head, rel, tail, rel_emb, out);
}